// Round 1
// baseline (227.212 us; speedup 1.0000x reference)
//
#include <hip/hip_runtime.h>
#include <hip/hip_fp16.h>
#include <cstdint>

// Problem constants
#define BB 8
#define NN 256
#define NC 5
#define NH 8
#define DIM 512
#define HD 64

typedef _Float16 half_t;
typedef _Float16 h8 __attribute__((ext_vector_type(8)));
typedef float f4 __attribute__((ext_vector_type(4)));
typedef uint32_t u4v __attribute__((ext_vector_type(4)));

__device__ __forceinline__ f4 mfma16(h8 a, h8 b, f4 c) {
  return __builtin_amdgcn_mfma_f32_16x16x32_f16(a, b, c, 0, 0, 0);
}

__device__ __forceinline__ h8 ld_f32x8_h8(const float* __restrict__ p) {
  float4 a = *(const float4*)p;
  float4 b = *(const float4*)(p + 4);
  h8 r;
  r[0] = (_Float16)a.x; r[1] = (_Float16)a.y; r[2] = (_Float16)a.z; r[3] = (_Float16)a.w;
  r[4] = (_Float16)b.x; r[5] = (_Float16)b.y; r[6] = (_Float16)b.z; r[7] = (_Float16)b.w;
  return r;
}

// relu(x) on 8 packed fp16 (2 per u32). mask = 0xffff where half is negative.
__device__ __forceinline__ h8 relu_pos_h8(h8 x) {
  u4v u = __builtin_bit_cast(u4v, x);
  const u4v k1 = {0x00010001u, 0x00010001u, 0x00010001u, 0x00010001u};
  u4v s = (u >> 15) & k1;
  u4v m = (s << 16) - s;
  u = u & ~m;
  return __builtin_bit_cast(h8, u);
}

// relu(-x) on 8 packed fp16
__device__ __forceinline__ h8 relu_neg_h8(h8 x) {
  u4v u = __builtin_bit_cast(u4v, x);
  const u4v k1 = {0x00010001u, 0x00010001u, 0x00010001u, 0x00010001u};
  const u4v ks = {0x80008000u, 0x80008000u, 0x80008000u, 0x80008000u};
  u4v s = (u >> 15) & k1;
  u4v m = (s << 16) - s;
  u = (u ^ ks) & m;
  return __builtin_bit_cast(h8, u);
}

// ---------------------------------------------------------------------------
// K1: out[M,512] (fp16) = A[M,512] (f32) @ W[512,512]^T (f32). 64x64 tile/WG.
// ---------------------------------------------------------------------------
__global__ __launch_bounds__(256) void proj_gemm(const float* __restrict__ A,
                                                 const float* __restrict__ W,
                                                 half_t* __restrict__ out) {
  const int tid = threadIdx.x;
  const int w = tid >> 6, lane = tid & 63;
  const int lr = lane & 15, lk = (lane >> 4) * 8, lg = lane >> 4;
  const int row0 = blockIdx.x * 64 + w * 16;
  const int col0 = blockIdx.y * 64;
  const f4 fz = {0.f, 0.f, 0.f, 0.f};
  f4 acc[4] = {fz, fz, fz, fz};
  const float* arow = A + (size_t)(row0 + lr) * DIM;
  for (int k0 = 0; k0 < DIM; k0 += 32) {
    h8 a = ld_f32x8_h8(arow + k0 + lk);
#pragma unroll
    for (int ct = 0; ct < 4; ++ct) {
      h8 b = ld_f32x8_h8(W + (size_t)(col0 + ct * 16 + lr) * DIM + k0 + lk);
      acc[ct] = mfma16(a, b, acc[ct]);
    }
  }
#pragma unroll
  for (int ct = 0; ct < 4; ++ct) {
    int col = col0 + ct * 16 + lr;
#pragma unroll
    for (int r = 0; r < 4; ++r) {
      int row = row0 + lg * 4 + r;
      out[(size_t)row * DIM + col] = (half_t)acc[ct][r];
    }
  }
}

// ---------------------------------------------------------------------------
// K2: per (b,c,h): a0 = 0.125 * q @ k^T  (write fp32 to d_out, fp16 to LDS),
// S = relu(-a0) @ relu(a0)^T, softmax over rows per column, weighted
// atomicAdd into tmp[B,H,N,N].
// LDS: a0s 256*256 fp16 (128KB, XOR-swizzled) + 2KB reduce scratch.
// ---------------------------------------------------------------------------
__global__ __launch_bounds__(512) void fused_attn(const half_t* __restrict__ q_h,
                                                  const half_t* __restrict__ k_h,
                                                  const float* __restrict__ weights,
                                                  float* __restrict__ a0_base,
                                                  float* __restrict__ tmp) {
  extern __shared__ char smem[];
  half_t* a0s = (half_t*)smem;                 // [256][256] swizzled
  float* scr = (float*)(smem + NN * NN * 2);   // [0:256) max, [256:512) sum

  const int id = blockIdx.x;
  const int b = id / (NC * NH);
  const int rem = id % (NC * NH);
  const int c = rem / NH;
  const int h = rem % NH;

  const int tid = threadIdx.x;
  const int w = tid >> 6, lane = tid & 63;
  const int lr = lane & 15, lk = (lane >> 4) * 8, lg = lane >> 4;
  const int n0 = w * 32;  // this wave's 32 rows

  const half_t* qbase = q_h + (size_t)(b * NN) * DIM + h * HD;
  const half_t* kbase = k_h + (size_t)(c * NN) * DIM + h * HD;
  float* a0out = a0_base + (size_t)((b * NC + c) * NH + h) * (NN * NN);

  const f4 fz = {0.f, 0.f, 0.f, 0.f};

  // ---- phase 1: a0 ----
  h8 aq[2][2];
#pragma unroll
  for (int rt = 0; rt < 2; ++rt)
#pragma unroll
    for (int kk = 0; kk < 2; ++kk)
      aq[rt][kk] = *(const h8*)(qbase + (size_t)(n0 + rt * 16 + lr) * DIM + kk * 32 + lk);

  for (int ct = 0; ct < 16; ++ct) {
    f4 acc0 = fz, acc1 = fz;
#pragma unroll
    for (int kk = 0; kk < 2; ++kk) {
      h8 bk = *(const h8*)(kbase + (size_t)(ct * 16 + lr) * DIM + kk * 32 + lk);
      acc0 = mfma16(aq[0][kk], bk, acc0);
      acc1 = mfma16(aq[1][kk], bk, acc1);
    }
    const int m = ct * 16 + lr;
#pragma unroll
    for (int r = 0; r < 4; ++r) {
      {
        int n = n0 + lg * 4 + r;
        float v = acc0[r] * 0.125f;
        a0out[n * NN + m] = v;
        a0s[(n * NN + m) ^ ((n & 7) << 3)] = (half_t)v;
      }
      {
        int n = n0 + 16 + lg * 4 + r;
        float v = acc1[r] * 0.125f;
        a0out[n * NN + m] = v;
        a0s[(n * NN + m) ^ ((n & 7) << 3)] = (half_t)v;
      }
    }
  }
  __syncthreads();

  // ---- phase 2: S panels + column softmax + weighted accumulate ----
  const float wgt = weights[(b * NH + h) * NC + c];
  float* tmpbh = tmp + (size_t)(b * NH + h) * (NN * NN);

  // hoist relu(-a0) rows for this wave across all panels (64 VGPRs)
  h8 La[2][8];
#pragma unroll
  for (int rt = 0; rt < 2; ++rt)
#pragma unroll
    for (int ks = 0; ks < 8; ++ks) {
      int row = n0 + rt * 16 + lr;
      int idx = (row * NN + ks * 32 + lk) ^ ((row & 7) << 3);
      La[rt][ks] = relu_neg_h8(*(const h8*)(a0s + idx));
    }

  for (int p = 0; p < 8; ++p) {
    const int m0 = p * 32;
    f4 acc[2][2] = {{fz, fz}, {fz, fz}};
#pragma unroll
    for (int ks = 0; ks < 8; ++ks) {
      int r0 = m0 + lr, r1 = m0 + 16 + lr;
      h8 b0 = relu_pos_h8(*(const h8*)(a0s + ((r0 * NN + ks * 32 + lk) ^ ((r0 & 7) << 3))));
      h8 b1 = relu_pos_h8(*(const h8*)(a0s + ((r1 * NN + ks * 32 + lk) ^ ((r1 & 7) << 3))));
      acc[0][0] = mfma16(La[0][ks], b0, acc[0][0]);
      acc[1][0] = mfma16(La[1][ks], b0, acc[1][0]);
      acc[0][1] = mfma16(La[0][ks], b1, acc[0][1]);
      acc[1][1] = mfma16(La[1][ks], b1, acc[1][1]);
    }

    // wave-local column max (over this wave's 32 rows)
    float cm[2];
#pragma unroll
    for (int ctp = 0; ctp < 2; ++ctp) {
      float v = -1e30f;
#pragma unroll
      for (int rt = 0; rt < 2; ++rt)
#pragma unroll
        for (int r = 0; r < 4; ++r) v = fmaxf(v, acc[rt][ctp][r]);
      v = fmaxf(v, __shfl_xor(v, 16, 64));
      v = fmaxf(v, __shfl_xor(v, 32, 64));
      cm[ctp] = v;
    }
    if (lane < 16) {
      scr[(0 * 8 + w) * 16 + lane] = cm[0];
      scr[(1 * 8 + w) * 16 + lane] = cm[1];
    }
    __syncthreads();
    float gm[2];
#pragma unroll
    for (int ctp = 0; ctp < 2; ++ctp) {
      float v = -1e30f;
#pragma unroll
      for (int ww = 0; ww < 8; ++ww) v = fmaxf(v, scr[(ctp * 8 + ww) * 16 + lr]);
      gm[ctp] = v;
    }

    // exp + wave-local column sum
    float cs[2];
#pragma unroll
    for (int ctp = 0; ctp < 2; ++ctp) {
      float s = 0.f;
#pragma unroll
      for (int rt = 0; rt < 2; ++rt)
#pragma unroll
        for (int r = 0; r < 4; ++r) {
          float e = __expf(acc[rt][ctp][r] - gm[ctp]);
          acc[rt][ctp][r] = e;
          s += e;
        }
      s += __shfl_xor(s, 16, 64);
      s += __shfl_xor(s, 32, 64);
      cs[ctp] = s;
    }
    if (lane < 16) {
      scr[256 + (0 * 8 + w) * 16 + lane] = cs[0];
      scr[256 + (1 * 8 + w) * 16 + lane] = cs[1];
    }
    __syncthreads();
    float sc[2];
#pragma unroll
    for (int ctp = 0; ctp < 2; ++ctp) {
      float s = 0.f;
#pragma unroll
      for (int ww = 0; ww < 8; ++ww) s += scr[256 + (ctp * 8 + ww) * 16 + lr];
      sc[ctp] = wgt / s;
    }

    // weighted accumulate into tmp
#pragma unroll
    for (int ctp = 0; ctp < 2; ++ctp) {
      int m = m0 + ctp * 16 + lr;
#pragma unroll
      for (int rt = 0; rt < 2; ++rt)
#pragma unroll
        for (int r = 0; r < 4; ++r) {
          int n = n0 + rt * 16 + lg * 4 + r;
          atomicAdd(tmpbh + n * NN + m, acc[rt][ctp][r] * sc[ctp]);
        }
    }
  }
}

// ---------------------------------------------------------------------------
// K3: out_head[b,h,n,d] (fp16) = tmp[b,h] @ v[b,h]   (256x256 @ 256x64)
// grid: (b,h,quarter) = 256 WGs; v staged transposed in LDS.
// ---------------------------------------------------------------------------
__global__ __launch_bounds__(256) void pv_gemm(const float* __restrict__ tmp,
                                               const half_t* __restrict__ v_h,
                                               half_t* __restrict__ out_head) {
  __shared__ half_t vts[HD * NN];  // [d][m], swizzled
  const int id = blockIdx.x;
  const int q4 = id & 3, h = (id >> 2) & 7, b = id >> 5;
  const int tid = threadIdx.x;
  const int w = tid >> 6, lane = tid & 63;
  const int lr = lane & 15, lk = (lane >> 4) * 8, lg = lane >> 4;

  // stage v^T
  const half_t* vb = v_h + (size_t)(b * NN) * DIM + h * HD;
  {
    const int mloc = tid >> 3;        // 0..31
    const int d0 = (tid & 7) * 8;     // 0..56
    for (int it = 0; it < 8; ++it) {
      int m = it * 32 + mloc;
      h8 vv = *(const h8*)(vb + (size_t)m * DIM + d0);
#pragma unroll
      for (int j = 0; j < 8; ++j) {
        int d = d0 + j;
        vts[(d * NN + m) ^ ((d & 7) << 3)] = vv[j];
      }
    }
  }
  __syncthreads();

  const int n0 = q4 * 64 + w * 16;
  const float* trow = tmp + (size_t)(b * NH + h) * (NN * NN);
  const f4 fz = {0.f, 0.f, 0.f, 0.f};
  f4 acc[4] = {fz, fz, fz, fz};
  for (int ks = 0; ks < 8; ++ks) {
    h8 a = ld_f32x8_h8(trow + (size_t)(n0 + lr) * NN + ks * 32 + lk);
#pragma unroll
    for (int ct = 0; ct < 4; ++ct) {
      int d = ct * 16 + lr;
      h8 bf = *(const h8*)(vts + ((d * NN + ks * 32 + lk) ^ ((d & 7) << 3)));
      acc[ct] = mfma16(a, bf, acc[ct]);
    }
  }
  half_t* ob = out_head + (size_t)(b * NH + h) * (NN * HD);
#pragma unroll
  for (int ct = 0; ct < 4; ++ct) {
    int d = ct * 16 + lr;
#pragma unroll
    for (int r = 0; r < 4; ++r) {
      int n = n0 + lg * 4 + r;
      ob[n * HD + d] = (half_t)acc[ct][r];
    }
  }
}

// ---------------------------------------------------------------------------
// K4: out0[b,i,:] = out_pre[b,i,:] @ proj_w^T + proj_b, where out_pre is the
// torch-style flat reshape of out_head: given (i,j): h=i>>5,
// n=((i&31)<<3)|(j>>6), d=j&63.
// ---------------------------------------------------------------------------
__global__ __launch_bounds__(256) void out_proj(const half_t* __restrict__ out_head,
                                                const float* __restrict__ pw,
                                                const float* __restrict__ pb,
                                                float* __restrict__ out0) {
  const int tid = threadIdx.x;
  const int w = tid >> 6, lane = tid & 63;
  const int lr = lane & 15, lk = (lane >> 4) * 8, lg = lane >> 4;
  const int row0 = blockIdx.x * 64 + w * 16;
  const int col0 = blockIdx.y * 64;
  const int r_ = row0 + lr;
  const int b = r_ >> 8, i = r_ & 255;
  const int hh = i >> 5;
  const f4 fz = {0.f, 0.f, 0.f, 0.f};
  f4 acc[4] = {fz, fz, fz, fz};
  for (int k0 = 0; k0 < DIM; k0 += 32) {
    const int k = k0 + lk;
    const int n = ((i & 31) << 3) | (k >> 6);
    const int d = k & 63;
    h8 a = *(const h8*)(out_head + (size_t)((b * NH + hh) * NN + n) * HD + d);
#pragma unroll
    for (int ct = 0; ct < 4; ++ct) {
      h8 bf = ld_f32x8_h8(pw + (size_t)(col0 + ct * 16 + lr) * DIM + k0 + lk);
      acc[ct] = mfma16(a, bf, acc[ct]);
    }
  }
#pragma unroll
  for (int ct = 0; ct < 4; ++ct) {
    int col = col0 + ct * 16 + lr;
    float bias = pb[col];
#pragma unroll
    for (int r = 0; r < 4; ++r) {
      int row = row0 + lg * 4 + r;
      out0[(size_t)row * DIM + col] = acc[ct][r] + bias;
    }
  }
}

// ---------------------------------------------------------------------------
extern "C" void kernel_launch(void* const* d_in, const int* in_sizes, int n_in,
                              void* d_out, int out_size, void* d_ws, size_t ws_size,
                              hipStream_t stream) {
  const float* x = (const float*)d_in[0];
  const float* anchors = (const float*)d_in[1];
  const float* weights = (const float*)d_in[2];
  const float* qk_w = (const float*)d_in[3];
  const float* v_w = (const float*)d_in[4];
  const float* proj_w = (const float*)d_in[5];
  const float* proj_b = (const float*)d_in[6];

  float* out0 = (float*)d_out;                       // [8,256,512]
  float* a0_out = out0 + (size_t)BB * NN * DIM;      // [8,5,8,256,256]

  char* ws = (char*)d_ws;
  half_t* q_h = (half_t*)ws;                                   // 2 MB
  half_t* k_h = (half_t*)(ws + (size_t)2 * 1024 * 1024);       // 1.25 MB
  half_t* v_h = (half_t*)(ws + (size_t)4 * 1024 * 1024);       // 2 MB
  half_t* out_head = (half_t*)(ws + (size_t)6 * 1024 * 1024);  // 2 MB
  float* tmp = (float*)(ws + (size_t)8 * 1024 * 1024);         // 16 MB

  hipMemsetAsync(tmp, 0, (size_t)BB * NH * NN * NN * 4, stream);

  proj_gemm<<<dim3(32, 8), 256, 0, stream>>>(x, qk_w, q_h);
  proj_gemm<<<dim3(20, 8), 256, 0, stream>>>(anchors, qk_w, k_h);
  proj_gemm<<<dim3(32, 8), 256, 0, stream>>>(x, v_w, v_h);

  const size_t lds_bytes = (size_t)NN * NN * 2 + 512 * 4;  // 133,120 B
  fused_attn<<<dim3(BB * NC * NH), 512, lds_bytes, stream>>>(q_h, k_h, weights,
                                                             a0_out, tmp);

  pv_gemm<<<dim3(256), 256, 0, stream>>>(tmp, v_h, out_head);

  out_proj<<<dim3(32, 8), 256, 0, stream>>>(out_head, proj_w, proj_b, out0);

  (void)in_sizes; (void)n_in; (void)out_size; (void)ws_size;
}

// Round 2
// 202.595 us; speedup vs baseline: 1.1215x; 1.1215x over previous
//
#include <hip/hip_runtime.h>
#include <hip/hip_fp16.h>
#include <cstdint>

// Problem constants
#define BB 8
#define NN 256
#define NC 5
#define NH 8
#define DIM 512
#define HD 64

typedef _Float16 half_t;
typedef _Float16 h8 __attribute__((ext_vector_type(8)));
typedef _Float16 h4 __attribute__((ext_vector_type(4)));
typedef float f4 __attribute__((ext_vector_type(4)));
typedef uint32_t u4v __attribute__((ext_vector_type(4)));

__device__ __forceinline__ f4 mfma16(h8 a, h8 b, f4 c) {
  return __builtin_amdgcn_mfma_f32_16x16x32_f16(a, b, c, 0, 0, 0);
}

__device__ __forceinline__ h8 ld_f32x8_h8(const float* __restrict__ p) {
  float4 a = *(const float4*)p;
  float4 b = *(const float4*)(p + 4);
  h8 r;
  r[0] = (_Float16)a.x; r[1] = (_Float16)a.y; r[2] = (_Float16)a.z; r[3] = (_Float16)a.w;
  r[4] = (_Float16)b.x; r[5] = (_Float16)b.y; r[6] = (_Float16)b.z; r[7] = (_Float16)b.w;
  return r;
}

// relu(x) on 8 packed fp16
__device__ __forceinline__ h8 relu_pos_h8(h8 x) {
  u4v u = __builtin_bit_cast(u4v, x);
  const u4v k1 = {0x00010001u, 0x00010001u, 0x00010001u, 0x00010001u};
  u4v s = (u >> 15) & k1;
  u4v m = (s << 16) - s;
  u = u & ~m;
  return __builtin_bit_cast(h8, u);
}

// relu(-x) on 8 packed fp16
__device__ __forceinline__ h8 relu_neg_h8(h8 x) {
  u4v u = __builtin_bit_cast(u4v, x);
  const u4v k1 = {0x00010001u, 0x00010001u, 0x00010001u, 0x00010001u};
  const u4v ks = {0x80008000u, 0x80008000u, 0x80008000u, 0x80008000u};
  u4v s = (u >> 15) & k1;
  u4v m = (s << 16) - s;
  u = (u ^ ks) & m;
  return __builtin_bit_cast(h8, u);
}

// Raw barrier: waits LDS only, does NOT drain vmcnt (global stores stay in flight).
__device__ __forceinline__ void barrier_lds() {
  __builtin_amdgcn_sched_barrier(0);
  asm volatile("s_waitcnt lgkmcnt(0)" ::: "memory");
  __builtin_amdgcn_s_barrier();
  asm volatile("" ::: "memory");
  __builtin_amdgcn_sched_barrier(0);
}

// ---------------------------------------------------------------------------
// K1: out[M,512] (fp16) = A[M,512] (f32) @ W[512,512]^T (f32). 64x64 tile/WG.
// ---------------------------------------------------------------------------
__global__ __launch_bounds__(256) void proj_gemm(const float* __restrict__ A,
                                                 const float* __restrict__ W,
                                                 half_t* __restrict__ out) {
  const int tid = threadIdx.x;
  const int w = tid >> 6, lane = tid & 63;
  const int lr = lane & 15, lk = (lane >> 4) * 8, lg = lane >> 4;
  const int row0 = blockIdx.x * 64 + w * 16;
  const int col0 = blockIdx.y * 64;
  const f4 fz = {0.f, 0.f, 0.f, 0.f};
  f4 acc[4] = {fz, fz, fz, fz};
  const float* arow = A + (size_t)(row0 + lr) * DIM;
  for (int k0 = 0; k0 < DIM; k0 += 32) {
    h8 a = ld_f32x8_h8(arow + k0 + lk);
#pragma unroll
    for (int ct = 0; ct < 4; ++ct) {
      h8 b = ld_f32x8_h8(W + (size_t)(col0 + ct * 16 + lr) * DIM + k0 + lk);
      acc[ct] = mfma16(a, b, acc[ct]);
    }
  }
#pragma unroll
  for (int ct = 0; ct < 4; ++ct) {
    int col = col0 + ct * 16 + lr;
#pragma unroll
    for (int r = 0; r < 4; ++r) {
      int row = row0 + lg * 4 + r;
      out[(size_t)row * DIM + col] = (half_t)acc[ct][r];
    }
  }
}

// ---------------------------------------------------------------------------
// K2 v2: per (b,c,h) block, 512 threads (8 waves), wave w owns rows n0=w*32.
//  phase1: a0^T = 0.125 * (k @ q^T) fragments -> fp16 LDS (h4 writes)
//  phase2a: stream fp32 a0 to global from LDS (coalesced x4, fire-and-forget)
//  phase2b: S = relu(-a0) @ relu(a0)^T, all 8 panels resident in VGPRs
//  softmax over columns (2 LDS-scratch reduction passes, raw barriers)
//  phase2c: U_c = (w_c * attn) @ v via LDS P-bounce + vts, h4 stores to ws
// LDS: a0s 128KB (reused by vts 32KB + pbuf 20KB after S) + scr 16KB.
// ---------------------------------------------------------------------------
__global__ __launch_bounds__(512, 1) void fused_attn2(const half_t* __restrict__ q_h,
                                                      const half_t* __restrict__ k_h,
                                                      const half_t* __restrict__ v_h,
                                                      const float* __restrict__ weights,
                                                      float* __restrict__ a0_base,
                                                      half_t* __restrict__ U) {
  extern __shared__ char smem[];
  half_t* a0s = (half_t*)smem;                       // [256][256] swizzled, 128KB
  float* scr = (float*)(smem + 131072);              // 2048 f32 (max)
  float* scr2 = (float*)(smem + 131072 + 8192);      // 2048 f32 (sum)
  half_t* vts = (half_t*)smem;                       // reuse: [64][256] swizzled, 32KB
  half_t* pbuf = (half_t*)smem + 32768;              // reuse: 8 waves x [32][40]

  const int id = blockIdx.x;
  const int b = id / (NC * NH);
  const int rem = id % (NC * NH);
  const int c = rem / NH;
  const int h = rem % NH;

  const int tid = threadIdx.x;
  const int w = tid >> 6, lane = tid & 63;
  const int lr = lane & 15, lk = (lane >> 4) * 8, lg = lane >> 4;
  const int n0 = w * 32;

  const half_t* qb = q_h + (size_t)(b * NN) * DIM + h * HD;
  const half_t* kb = k_h + (size_t)(c * NN) * DIM + h * HD;
  float* a0out = a0_base + (size_t)((b * NC + c) * NH + h) * (NN * NN);
  const float wgt = weights[(b * NH + h) * NC + c];

  const f4 fz = {0.f, 0.f, 0.f, 0.f};

  // ---- phase 1: a0^T fragments -> LDS fp16 ----
  h8 qf[2][2];
#pragma unroll
  for (int bt = 0; bt < 2; ++bt)
#pragma unroll
    for (int kk = 0; kk < 2; ++kk)
      qf[bt][kk] = *(const h8*)(qb + (size_t)(n0 + bt * 16 + lr) * DIM + kk * 32 + lk);

#pragma unroll
  for (int mt = 0; mt < 16; ++mt) {
    h8 kf0 = *(const h8*)(kb + (size_t)(mt * 16 + lr) * DIM + lk);
    h8 kf1 = *(const h8*)(kb + (size_t)(mt * 16 + lr) * DIM + 32 + lk);
    f4 acc0 = fz, acc1 = fz;
    acc0 = mfma16(kf0, qf[0][0], acc0);
    acc0 = mfma16(kf1, qf[0][1], acc0);
    acc1 = mfma16(kf0, qf[1][0], acc1);
    acc1 = mfma16(kf1, qf[1][1], acc1);
    // D: row = m = mt*16 + lg*4 + r (consecutive r!), col = n = n0 + bt*16 + lr
    const int mb = mt * 16 + lg * 4;
    h4 w0, w1;
#pragma unroll
    for (int r = 0; r < 4; ++r) {
      w0[r] = (_Float16)(acc0[r] * 0.125f);
      w1[r] = (_Float16)(acc1[r] * 0.125f);
    }
    const int na = n0 + lr, nb2 = n0 + 16 + lr;
    *(h4*)(a0s + ((na * NN + mb) ^ ((na & 7) << 3))) = w0;
    *(h4*)(a0s + ((nb2 * NN + mb) ^ ((nb2 & 7) << 3))) = w1;
  }
  barrier_lds();

  // ---- phase 2a: stream a0 (fp32) to global; drains under S compute ----
#pragma unroll
  for (int it = 0; it < 16; ++it) {
    int idx = it * 4096 + tid * 8;
    int n = idx >> 8, m = idx & 255;
    h8 hv = *(const h8*)(a0s + ((n * NN + m) ^ ((n & 7) << 3)));
    float4 f0, f1;
    f0.x = (float)hv[0]; f0.y = (float)hv[1]; f0.z = (float)hv[2]; f0.w = (float)hv[3];
    f1.x = (float)hv[4]; f1.y = (float)hv[5]; f1.z = (float)hv[6]; f1.w = (float)hv[7];
    *(float4*)(a0out + idx) = f0;
    *(float4*)(a0out + idx + 4) = f1;
  }

  // ---- phase 2b: S = L @ R^T, all panels resident ----
  h8 La[2][8];
#pragma unroll
  for (int rt = 0; rt < 2; ++rt)
#pragma unroll
    for (int kc = 0; kc < 8; ++kc) {
      int row = n0 + rt * 16 + lr;
      La[rt][kc] = relu_neg_h8(*(const h8*)(a0s + ((row * NN + kc * 32 + lk) ^ ((row & 7) << 3))));
    }

  f4 sacc[8][2][2];
#pragma unroll
  for (int p = 0; p < 8; ++p)
#pragma unroll
    for (int i = 0; i < 2; ++i)
#pragma unroll
      for (int j = 0; j < 2; ++j) sacc[p][i][j] = fz;

#pragma unroll
  for (int p = 0; p < 8; ++p) {
#pragma unroll
    for (int kc = 0; kc < 8; ++kc) {
      const int r0 = p * 32 + lr, r1 = p * 32 + 16 + lr;
      h8 R0 = relu_pos_h8(*(const h8*)(a0s + ((r0 * NN + kc * 32 + lk) ^ ((r0 & 7) << 3))));
      h8 R1 = relu_pos_h8(*(const h8*)(a0s + ((r1 * NN + kc * 32 + lk) ^ ((r1 & 7) << 3))));
      sacc[p][0][0] = mfma16(La[0][kc], R0, sacc[p][0][0]);
      sacc[p][0][1] = mfma16(La[1][kc], R0, sacc[p][0][1]);
      sacc[p][1][0] = mfma16(La[0][kc], R1, sacc[p][1][0]);
      sacc[p][1][1] = mfma16(La[1][kc], R1, sacc[p][1][1]);
    }
  }

  // ---- column max (over n) ----
#pragma unroll
  for (int p = 0; p < 8; ++p)
#pragma unroll
    for (int ctp = 0; ctp < 2; ++ctp) {
      float v = -3e38f;
#pragma unroll
      for (int rt = 0; rt < 2; ++rt)
#pragma unroll
        for (int r = 0; r < 4; ++r) v = fmaxf(v, sacc[p][ctp][rt][r]);
      v = fmaxf(v, __shfl_xor(v, 16, 64));
      v = fmaxf(v, __shfl_xor(v, 32, 64));
      if (lane < 16) scr[(p * 32 + ctp * 16 + lr) * 8 + w] = v;
    }
  barrier_lds();

  float gm[8][2];
#pragma unroll
  for (int p = 0; p < 8; ++p)
#pragma unroll
    for (int ctp = 0; ctp < 2; ++ctp) {
      int m = p * 32 + ctp * 16 + lr;
      f4 x = *(const f4*)(scr + m * 8);
      f4 y = *(const f4*)(scr + m * 8 + 4);
      float v = fmaxf(fmaxf(fmaxf(x[0], x[1]), fmaxf(x[2], x[3])),
                      fmaxf(fmaxf(y[0], y[1]), fmaxf(y[2], y[3])));
      gm[p][ctp] = v;
    }

  // ---- exp + column sums ----
#pragma unroll
  for (int p = 0; p < 8; ++p)
#pragma unroll
    for (int ctp = 0; ctp < 2; ++ctp) {
      float s = 0.f;
#pragma unroll
      for (int rt = 0; rt < 2; ++rt)
#pragma unroll
        for (int r = 0; r < 4; ++r) {
          float e = __expf(sacc[p][ctp][rt][r] - gm[p][ctp]);
          sacc[p][ctp][rt][r] = e;
          s += e;
        }
      s += __shfl_xor(s, 16, 64);
      s += __shfl_xor(s, 32, 64);
      if (lane < 16) scr2[(p * 32 + ctp * 16 + lr) * 8 + w] = s;
    }
  barrier_lds();

  float sc[8][2];
#pragma unroll
  for (int p = 0; p < 8; ++p)
#pragma unroll
    for (int ctp = 0; ctp < 2; ++ctp) {
      int m = p * 32 + ctp * 16 + lr;
      f4 x = *(const f4*)(scr2 + m * 8);
      f4 y = *(const f4*)(scr2 + m * 8 + 4);
      float s = (x[0] + x[1]) + (x[2] + x[3]) + (y[0] + y[1]) + (y[2] + y[3]);
      sc[p][ctp] = wgt / s;
    }

  // ---- phase 2c: stage v^T into (dead) a0s region ----
  {
    const half_t* vb = v_h + (size_t)(b * NN) * DIM + h * HD;
    const int mloc = tid >> 3;          // 0..63
    const int d0 = (tid & 7) * 8;       // 0..56
#pragma unroll
    for (int it = 0; it < 4; ++it) {
      int m = it * 64 + mloc;
      h8 vv = *(const h8*)(vb + (size_t)m * DIM + d0);
#pragma unroll
      for (int j = 0; j < 8; ++j) {
        int d = d0 + j;
        vts[(d * NN + m) ^ ((d & 7) << 3)] = vv[j];
      }
    }
  }
  barrier_lds();

  // ---- PV: out^T[d,n] += v^T[d,m] @ P^T[m,n], per panel ----
  half_t* pbw = pbuf + w * 1280;  // [32][40] fp16, stride 40 (2-way max)
  f4 uacc[4][2];
#pragma unroll
  for (int dt = 0; dt < 4; ++dt)
#pragma unroll
    for (int nt = 0; nt < 2; ++nt) uacc[dt][nt] = fz;

#pragma unroll
  for (int p = 0; p < 8; ++p) {
    // bounce P tile (scaled fp16) through per-wave LDS
#pragma unroll
    for (int ctp = 0; ctp < 2; ++ctp)
#pragma unroll
      for (int rt = 0; rt < 2; ++rt)
#pragma unroll
        for (int r = 0; r < 4; ++r) {
          int nloc = rt * 16 + lg * 4 + r;
          int mloc = ctp * 16 + lr;
          pbw[nloc * 40 + mloc] = (_Float16)(sacc[p][ctp][rt][r] * sc[p][ctp]);
        }
    h8 pf0 = *(const h8*)(pbw + (0 + lr) * 40 + lk);
    h8 pf1 = *(const h8*)(pbw + (16 + lr) * 40 + lk);
#pragma unroll
    for (int dt = 0; dt < 4; ++dt) {
      int d = dt * 16 + lr;
      h8 vf = *(const h8*)(vts + ((d * NN + p * 32 + lk) ^ ((d & 7) << 3)));
      uacc[dt][0] = mfma16(vf, pf0, uacc[dt][0]);
      uacc[dt][1] = mfma16(vf, pf1, uacc[dt][1]);
    }
  }

  // ---- store U_c (fp16) ----
  half_t* Ub = U + (size_t)((b * NC + c) * NH + h) * (NN * HD);
#pragma unroll
  for (int dt = 0; dt < 4; ++dt)
#pragma unroll
    for (int nt = 0; nt < 2; ++nt) {
      int d = dt * 16 + lg * 4;
      int n = n0 + nt * 16 + lr;
      h4 hv;
#pragma unroll
      for (int r = 0; r < 4; ++r) hv[r] = (_Float16)uacc[dt][nt][r];
      *(h4*)(Ub + (size_t)n * HD + d) = hv;
    }
}

// ---------------------------------------------------------------------------
// K3: out_head[b,h] = sum_c U[(b,c,h)]  (weights already folded into U)
// ---------------------------------------------------------------------------
__global__ __launch_bounds__(256) void reduce_u(const half_t* __restrict__ U,
                                                half_t* __restrict__ out_head) {
  int t = blockIdx.x * 256 + threadIdx.x;  // 131072 threads
  int bh = t >> 11;
  int e = (t & 2047) * 8;
  int b = bh >> 3, h = bh & 7;
  float acc[8] = {0.f, 0.f, 0.f, 0.f, 0.f, 0.f, 0.f, 0.f};
#pragma unroll
  for (int c = 0; c < NC; ++c) {
    h8 u = *(const h8*)(U + (size_t)((b * NC + c) * NH + h) * (NN * HD) + e);
#pragma unroll
    for (int j = 0; j < 8; ++j) acc[j] += (float)u[j];
  }
  h8 o;
#pragma unroll
  for (int j = 0; j < 8; ++j) o[j] = (_Float16)acc[j];
  *(h8*)(out_head + (size_t)bh * (NN * HD) + e) = o;
}

// ---------------------------------------------------------------------------
// K4: out0 = reshape(out_head) @ proj_w^T + proj_b
// ---------------------------------------------------------------------------
__global__ __launch_bounds__(256) void out_proj(const half_t* __restrict__ out_head,
                                                const float* __restrict__ pw,
                                                const float* __restrict__ pb,
                                                float* __restrict__ out0) {
  const int tid = threadIdx.x;
  const int w = tid >> 6, lane = tid & 63;
  const int lr = lane & 15, lk = (lane >> 4) * 8, lg = lane >> 4;
  const int row0 = blockIdx.x * 64 + w * 16;
  const int col0 = blockIdx.y * 64;
  const int r_ = row0 + lr;
  const int b = r_ >> 8, i = r_ & 255;
  const int hh = i >> 5;
  const f4 fz = {0.f, 0.f, 0.f, 0.f};
  f4 acc[4] = {fz, fz, fz, fz};
  for (int k0 = 0; k0 < DIM; k0 += 32) {
    const int k = k0 + lk;
    const int n = ((i & 31) << 3) | (k >> 6);
    const int d = k & 63;
    h8 a = *(const h8*)(out_head + (size_t)((b * NH + hh) * NN + n) * HD + d);
#pragma unroll
    for (int ct = 0; ct < 4; ++ct) {
      h8 bf = ld_f32x8_h8(pw + (size_t)(col0 + ct * 16 + lr) * DIM + k0 + lk);
      acc[ct] = mfma16(a, bf, acc[ct]);
    }
  }
#pragma unroll
  for (int ct = 0; ct < 4; ++ct) {
    int col = col0 + ct * 16 + lr;
    float bias = pb[col];
#pragma unroll
    for (int r = 0; r < 4; ++r) {
      int row = row0 + lg * 4 + r;
      out0[(size_t)row * DIM + col] = acc[ct][r] + bias;
    }
  }
}

// ---------------------------------------------------------------------------
extern "C" void kernel_launch(void* const* d_in, const int* in_sizes, int n_in,
                              void* d_out, int out_size, void* d_ws, size_t ws_size,
                              hipStream_t stream) {
  const float* x = (const float*)d_in[0];
  const float* anchors = (const float*)d_in[1];
  const float* weights = (const float*)d_in[2];
  const float* qk_w = (const float*)d_in[3];
  const float* v_w = (const float*)d_in[4];
  const float* proj_w = (const float*)d_in[5];
  const float* proj_b = (const float*)d_in[6];

  float* out0 = (float*)d_out;                       // [8,256,512]
  float* a0_out = out0 + (size_t)BB * NN * DIM;      // [8,5,8,256,256]

  char* ws = (char*)d_ws;
  half_t* q_h = (half_t*)ws;                                   // 2 MB
  half_t* k_h = (half_t*)(ws + (size_t)2 * 1024 * 1024);       // 1.25 MB
  half_t* v_h = (half_t*)(ws + (size_t)4 * 1024 * 1024);       // 2 MB
  half_t* out_head = (half_t*)(ws + (size_t)6 * 1024 * 1024);  // 2 MB
  half_t* U = (half_t*)(ws + (size_t)8 * 1024 * 1024);         // 10 MB

  proj_gemm<<<dim3(32, 8), 256, 0, stream>>>(x, qk_w, q_h);
  proj_gemm<<<dim3(20, 8), 256, 0, stream>>>(anchors, qk_w, k_h);
  proj_gemm<<<dim3(32, 8), 256, 0, stream>>>(x, v_w, v_h);

  const size_t lds_bytes = 131072 + 16384;  // a0s + scr/scr2 = 147,456 B
  fused_attn2<<<dim3(BB * NC * NH), 512, lds_bytes, stream>>>(q_h, k_h, v_h, weights,
                                                              a0_out, U);

  reduce_u<<<dim3(512), 256, 0, stream>>>(U, out_head);

  out_proj<<<dim3(32, 8), 256, 0, stream>>>(out_head, proj_w, proj_b, out0);

  (void)in_sizes; (void)n_in; (void)out_size; (void)ws_size;
}

// Round 3
// 159.511 us; speedup vs baseline: 1.4244x; 1.2701x over previous
//
#include <hip/hip_runtime.h>
#include <hip/hip_fp16.h>
#include <cstdint>

// Problem constants
#define BB 8
#define NN 256
#define NC 5
#define NH 8
#define DIM 512
#define HD 64

typedef _Float16 half_t;
typedef _Float16 h8 __attribute__((ext_vector_type(8)));
typedef _Float16 h4 __attribute__((ext_vector_type(4)));
typedef float f4 __attribute__((ext_vector_type(4)));
typedef uint32_t u4v __attribute__((ext_vector_type(4)));

__device__ __forceinline__ f4 mfma16(h8 a, h8 b, f4 c) {
  return __builtin_amdgcn_mfma_f32_16x16x32_f16(a, b, c, 0, 0, 0);
}

__device__ __forceinline__ h8 ld_f32x8_h8(const float* __restrict__ p) {
  float4 a = *(const float4*)p;
  float4 b = *(const float4*)(p + 4);
  h8 r;
  r[0] = (_Float16)a.x; r[1] = (_Float16)a.y; r[2] = (_Float16)a.z; r[3] = (_Float16)a.w;
  r[4] = (_Float16)b.x; r[5] = (_Float16)b.y; r[6] = (_Float16)b.z; r[7] = (_Float16)b.w;
  return r;
}

// relu(x) on 8 packed fp16
__device__ __forceinline__ h8 relu_pos_h8(h8 x) {
  u4v u = __builtin_bit_cast(u4v, x);
  const u4v k1 = {0x00010001u, 0x00010001u, 0x00010001u, 0x00010001u};
  u4v s = (u >> 15) & k1;
  u4v m = (s << 16) - s;
  u = u & ~m;
  return __builtin_bit_cast(h8, u);
}

// relu(-x) on 8 packed fp16
__device__ __forceinline__ h8 relu_neg_h8(h8 x) {
  u4v u = __builtin_bit_cast(u4v, x);
  const u4v k1 = {0x00010001u, 0x00010001u, 0x00010001u, 0x00010001u};
  const u4v ks = {0x80008000u, 0x80008000u, 0x80008000u, 0x80008000u};
  u4v s = (u >> 15) & k1;
  u4v m = (s << 16) - s;
  u = (u ^ ks) & m;
  return __builtin_bit_cast(h8, u);
}

// Raw barrier: waits LDS only, does NOT drain vmcnt (global stores stay in flight).
__device__ __forceinline__ void barrier_lds() {
  __builtin_amdgcn_sched_barrier(0);
  asm volatile("s_waitcnt lgkmcnt(0)" ::: "memory");
  __builtin_amdgcn_s_barrier();
  asm volatile("" ::: "memory");
  __builtin_amdgcn_sched_barrier(0);
}

// ---------------------------------------------------------------------------
// K1: all three projections in one launch.
//   bx <  32: q  = x @ qk_w^T       -> q_h [2048][512] fp16
//   bx <  52: k  = anchors @ qk_w^T -> k_h [1280][512] fp16
//   else    : vT = (x @ v_w^T)^T    -> vT  [512][2048] fp16  ([h*64+d][b*256+m])
// ---------------------------------------------------------------------------
__global__ __launch_bounds__(256) void proj_all(const float* __restrict__ x,
                                                const float* __restrict__ anchors,
                                                const float* __restrict__ qk_w,
                                                const float* __restrict__ v_w,
                                                half_t* __restrict__ q_h,
                                                half_t* __restrict__ k_h,
                                                half_t* __restrict__ vT) {
  const int bx = blockIdx.x, by = blockIdx.y;
  const int tid = threadIdx.x;
  const int w = tid >> 6, lane = tid & 63;
  const int lr = lane & 15, lk = (lane >> 4) * 8, lg = lane >> 4;

  const float* A;
  const float* W;
  int mode, rt0;
  if (bx < 32)      { A = x;       W = qk_w; mode = 0; rt0 = bx * 64; }
  else if (bx < 52) { A = anchors; W = qk_w; mode = 1; rt0 = (bx - 32) * 64; }
  else              { A = x;       W = v_w;  mode = 2; rt0 = (bx - 52) * 64; }

  const int row0 = rt0 + w * 16;
  const int col0 = by * 64;
  const f4 fz = {0.f, 0.f, 0.f, 0.f};
  f4 acc[4] = {fz, fz, fz, fz};
  const float* arow = A + (size_t)(row0 + lr) * DIM;

  if (mode != 2) {
    for (int k0 = 0; k0 < DIM; k0 += 32) {
      h8 a = ld_f32x8_h8(arow + k0 + lk);
#pragma unroll
      for (int ct = 0; ct < 4; ++ct) {
        h8 b = ld_f32x8_h8(W + (size_t)(col0 + ct * 16 + lr) * DIM + k0 + lk);
        acc[ct] = mfma16(a, b, acc[ct]);
      }
    }
    half_t* out = (mode == 0) ? q_h : k_h;
#pragma unroll
    for (int ct = 0; ct < 4; ++ct) {
      int col = col0 + ct * 16 + lr;
#pragma unroll
      for (int r = 0; r < 4; ++r) {
        int row = row0 + lg * 4 + r;
        out[(size_t)row * DIM + col] = (half_t)acc[ct][r];
      }
    }
  } else {
    // swapped operands: D[i=W-row(col)][j=A-row(xrow)]
    for (int k0 = 0; k0 < DIM; k0 += 32) {
      h8 a = ld_f32x8_h8(arow + k0 + lk);
#pragma unroll
      for (int ct = 0; ct < 4; ++ct) {
        h8 b = ld_f32x8_h8(W + (size_t)(col0 + ct * 16 + lr) * DIM + k0 + lk);
        acc[ct] = mfma16(b, a, acc[ct]);
      }
    }
    const int xrow = row0 + lr;
#pragma unroll
    for (int ct = 0; ct < 4; ++ct) {
#pragma unroll
      for (int r = 0; r < 4; ++r) {
        int col = col0 + ct * 16 + lg * 4 + r;  // = h*64 + d
        vT[(size_t)col * (BB * NN) + xrow] = (half_t)acc[ct][r];
      }
    }
  }
}

// ---------------------------------------------------------------------------
// K2 v3: per (b,c,h) block, 512 threads (8 waves), wave w owns rows n0=w*32.
//  phase1: a0 fragments -> fp16 LDS (h4 writes, XOR-swizzled)
//  panel loop p=0..7 (32 columns each), per panel:
//    - prefetch vT B-fragments from global (L2-hot)
//    - S panel = relu(-a0)@relu(a0)^T  (16 ds_read_b128 + 32 MFMA)
//    - 2/16 of the a0 fp32 global store (spread; drains under compute)
//    - softmax: local max+sum -> (m_w,s_w) pair in LDS, ONE barrier, combine
//    - P bounce through per-wave LDS, PV MFMA into uacc
//  store U_c = (w_c*attn)@v as fp16.
// LDS: a0s 128KB + scr 4.25KB (ping-pong) + pbuf 20KB = 155,904 B. 1 blk/CU.
// ---------------------------------------------------------------------------
__global__ __launch_bounds__(512, 1) void fused_attn3(const half_t* __restrict__ q_h,
                                                      const half_t* __restrict__ k_h,
                                                      const half_t* __restrict__ vT,
                                                      const float* __restrict__ weights,
                                                      float* __restrict__ a0_base,
                                                      half_t* __restrict__ U) {
  extern __shared__ char smem[];
  half_t* a0s = (half_t*)smem;                     // [256][256] swizzled, 131072 B
  float2* scrF = (float2*)(smem + 131072);         // 2 regions x 8 waves x 34 pairs
  half_t* pbuf = (half_t*)(smem + 131072 + 4352);  // 8 waves x [32][40]

  const int id = blockIdx.x;
  const int b = id / (NC * NH);
  const int rem = id % (NC * NH);
  const int c = rem / NH;
  const int h = rem % NH;

  const int tid = threadIdx.x;
  const int w = tid >> 6, lane = tid & 63;
  const int lr = lane & 15, lk = (lane >> 4) * 8, lg = lane >> 4;
  const int n0 = w * 32;

  const half_t* qb = q_h + (size_t)(b * NN) * DIM + h * HD;
  const half_t* kb = k_h + (size_t)(c * NN) * DIM + h * HD;
  const half_t* vTb = vT + (size_t)(h * HD) * (BB * NN) + b * NN;
  float* a0out = a0_base + (size_t)((b * NC + c) * NH + h) * (NN * NN);
  const float wgt = weights[(b * NH + h) * NC + c];

  const f4 fz = {0.f, 0.f, 0.f, 0.f};

  // ---- phase 1: a0 fragments -> LDS fp16 ----
  h8 qf[2][2];
#pragma unroll
  for (int bt = 0; bt < 2; ++bt)
#pragma unroll
    for (int kk = 0; kk < 2; ++kk)
      qf[bt][kk] = *(const h8*)(qb + (size_t)(n0 + bt * 16 + lr) * DIM + kk * 32 + lk);

#pragma unroll
  for (int mt = 0; mt < 16; ++mt) {
    h8 kf0 = *(const h8*)(kb + (size_t)(mt * 16 + lr) * DIM + lk);
    h8 kf1 = *(const h8*)(kb + (size_t)(mt * 16 + lr) * DIM + 32 + lk);
    f4 acc0 = fz, acc1 = fz;
    acc0 = mfma16(kf0, qf[0][0], acc0);
    acc0 = mfma16(kf1, qf[0][1], acc0);
    acc1 = mfma16(kf0, qf[1][0], acc1);
    acc1 = mfma16(kf1, qf[1][1], acc1);
    // D[i=m][j=n]: lane j=lr -> n, i=lg*4+r -> m (consecutive r)
    const int mb = mt * 16 + lg * 4;
    h4 w0, w1;
#pragma unroll
    for (int r = 0; r < 4; ++r) {
      w0[r] = (_Float16)(acc0[r] * 0.125f);
      w1[r] = (_Float16)(acc1[r] * 0.125f);
    }
    const int na = n0 + lr, nb2 = n0 + 16 + lr;
    *(h4*)(a0s + ((na * NN + mb) ^ ((na & 7) << 3))) = w0;
    *(h4*)(a0s + ((nb2 * NN + mb) ^ ((nb2 & 7) << 3))) = w1;
  }
  barrier_lds();

  // ---- hoist L = relu(-a0) for this wave's 32 rows (64 VGPRs) ----
  h8 La[2][8];
#pragma unroll
  for (int rt = 0; rt < 2; ++rt)
#pragma unroll
    for (int kc = 0; kc < 8; ++kc) {
      int row = n0 + rt * 16 + lr;
      La[rt][kc] = relu_neg_h8(*(const h8*)(a0s + ((row * NN + kc * 32 + lk) ^ ((row & 7) << 3))));
    }

  half_t* pbw = pbuf + w * 1280;  // [32][40]
  f4 uacc[4][2];
#pragma unroll
  for (int dt = 0; dt < 4; ++dt)
#pragma unroll
    for (int nt = 0; nt < 2; ++nt) uacc[dt][nt] = fz;

#pragma unroll 1
  for (int p = 0; p < 8; ++p) {
    // prefetch v^T B-fragments for this panel (used after softmax)
    h8 vf[4];
#pragma unroll
    for (int dt = 0; dt < 4; ++dt)
      vf[dt] = *(const h8*)(vTb + (size_t)(dt * 16 + lr) * (BB * NN) + p * 32 + lk);

    // S panel: sacc[ctp][rt], D[i=n(rt)][j=m(ctp)]
    f4 sacc[2][2] = {{fz, fz}, {fz, fz}};
#pragma unroll
    for (int kc = 0; kc < 8; ++kc) {
      const int r0 = p * 32 + lr, r1 = p * 32 + 16 + lr;
      h8 R0 = relu_pos_h8(*(const h8*)(a0s + ((r0 * NN + kc * 32 + lk) ^ ((r0 & 7) << 3))));
      h8 R1 = relu_pos_h8(*(const h8*)(a0s + ((r1 * NN + kc * 32 + lk) ^ ((r1 & 7) << 3))));
      sacc[0][0] = mfma16(La[0][kc], R0, sacc[0][0]);
      sacc[0][1] = mfma16(La[1][kc], R0, sacc[0][1]);
      sacc[1][0] = mfma16(La[0][kc], R1, sacc[1][0]);
      sacc[1][1] = mfma16(La[1][kc], R1, sacc[1][1]);
    }

    // spread a0 fp32 store: 2 of 16 chunks per panel (reads stable a0s)
#pragma unroll
    for (int it2 = 0; it2 < 2; ++it2) {
      int idx = (p * 2 + it2) * 4096 + tid * 8;
      int n = idx >> 8, m = idx & 255;
      h8 hv = *(const h8*)(a0s + ((n * NN + m) ^ ((n & 7) << 3)));
      float4 f0, f1;
      f0.x = (float)hv[0]; f0.y = (float)hv[1]; f0.z = (float)hv[2]; f0.w = (float)hv[3];
      f1.x = (float)hv[4]; f1.y = (float)hv[5]; f1.z = (float)hv[6]; f1.w = (float)hv[7];
      *(float4*)(a0out + idx) = f0;
      *(float4*)(a0out + idx + 4) = f1;
    }

    // softmax: wave-local max+sum (no barrier), then one combine barrier
    float mw[2], sw[2];
#pragma unroll
    for (int ctp = 0; ctp < 2; ++ctp) {
      float v = -3e38f;
#pragma unroll
      for (int rt = 0; rt < 2; ++rt)
#pragma unroll
        for (int r = 0; r < 4; ++r) v = fmaxf(v, sacc[ctp][rt][r]);
      v = fmaxf(v, __shfl_xor(v, 16, 64));
      v = fmaxf(v, __shfl_xor(v, 32, 64));
      mw[ctp] = v;
      float s = 0.f;
#pragma unroll
      for (int rt = 0; rt < 2; ++rt)
#pragma unroll
        for (int r = 0; r < 4; ++r) {
          float e = __expf(sacc[ctp][rt][r] - v);
          sacc[ctp][rt][r] = e;
          s += e;
        }
      s += __shfl_xor(s, 16, 64);
      s += __shfl_xor(s, 32, 64);
      sw[ctp] = s;
    }
    float2* sp = scrF + (p & 1) * 272;
    if (lane < 16) {
      float2 t0; t0.x = mw[0]; t0.y = sw[0];
      float2 t1; t1.x = mw[1]; t1.y = sw[1];
      sp[w * 34 + lr] = t0;
      sp[w * 34 + 16 + lr] = t1;
    }
    barrier_lds();

    float fac[2];
#pragma unroll
    for (int ctp = 0; ctp < 2; ++ctp) {
      float2 t[8];
      float gm = -3e38f;
#pragma unroll
      for (int ww = 0; ww < 8; ++ww) {
        t[ww] = sp[ww * 34 + ctp * 16 + lr];
        gm = fmaxf(gm, t[ww].x);
      }
      float sg = 0.f;
#pragma unroll
      for (int ww = 0; ww < 8; ++ww) sg += t[ww].y * __expf(t[ww].x - gm);
      fac[ctp] = __expf(mw[ctp] - gm) * wgt / sg;
    }

    // P bounce through per-wave LDS: pbw[nloc][mloc]
#pragma unroll
    for (int ctp = 0; ctp < 2; ++ctp) {
      const int mloc = ctp * 16 + lr;
#pragma unroll
      for (int rt = 0; rt < 2; ++rt)
#pragma unroll
        for (int r = 0; r < 4; ++r) {
          int nloc = rt * 16 + lg * 4 + r;
          pbw[nloc * 40 + mloc] = (_Float16)(sacc[ctp][rt][r] * fac[ctp]);
        }
    }
    h8 pf0 = *(const h8*)(pbw + lr * 40 + lk);
    h8 pf1 = *(const h8*)(pbw + (16 + lr) * 40 + lk);
#pragma unroll
    for (int dt = 0; dt < 4; ++dt) {
      uacc[dt][0] = mfma16(vf[dt], pf0, uacc[dt][0]);
      uacc[dt][1] = mfma16(vf[dt], pf1, uacc[dt][1]);
    }
  }

  // ---- store U_c (fp16): D[i=d][j=n] ----
  half_t* Ub = U + (size_t)((b * NC + c) * NH + h) * (NN * HD);
#pragma unroll
  for (int dt = 0; dt < 4; ++dt)
#pragma unroll
    for (int nt = 0; nt < 2; ++nt) {
      int d = dt * 16 + lg * 4;
      int n = n0 + nt * 16 + lr;
      h4 hv;
#pragma unroll
      for (int r = 0; r < 4; ++r) hv[r] = (_Float16)uacc[dt][nt][r];
      *(h4*)(Ub + (size_t)n * HD + d) = hv;
    }
}

// ---------------------------------------------------------------------------
// K3: out_head[b,h] = sum_c U[(b,c,h)]  (weights already folded into U)
// ---------------------------------------------------------------------------
__global__ __launch_bounds__(256) void reduce_u(const half_t* __restrict__ U,
                                                half_t* __restrict__ out_head) {
  int t = blockIdx.x * 256 + threadIdx.x;  // 131072 threads
  int bh = t >> 11;
  int e = (t & 2047) * 8;
  int b = bh >> 3, h = bh & 7;
  float acc[8] = {0.f, 0.f, 0.f, 0.f, 0.f, 0.f, 0.f, 0.f};
#pragma unroll
  for (int c = 0; c < NC; ++c) {
    h8 u = *(const h8*)(U + (size_t)((b * NC + c) * NH + h) * (NN * HD) + e);
#pragma unroll
    for (int j = 0; j < 8; ++j) acc[j] += (float)u[j];
  }
  h8 o;
#pragma unroll
  for (int j = 0; j < 8; ++j) o[j] = (_Float16)acc[j];
  *(h8*)(out_head + (size_t)bh * (NN * HD) + e) = o;
}

// ---------------------------------------------------------------------------
// K4: out0 = reshape(out_head) @ proj_w^T + proj_b
// ---------------------------------------------------------------------------
__global__ __launch_bounds__(256) void out_proj(const half_t* __restrict__ out_head,
                                                const float* __restrict__ pw,
                                                const float* __restrict__ pb,
                                                float* __restrict__ out0) {
  const int tid = threadIdx.x;
  const int w = tid >> 6, lane = tid & 63;
  const int lr = lane & 15, lk = (lane >> 4) * 8, lg = lane >> 4;
  const int row0 = blockIdx.x * 64 + w * 16;
  const int col0 = blockIdx.y * 64;
  const int r_ = row0 + lr;
  const int b = r_ >> 8, i = r_ & 255;
  const int hh = i >> 5;
  const f4 fz = {0.f, 0.f, 0.f, 0.f};
  f4 acc[4] = {fz, fz, fz, fz};
  for (int k0 = 0; k0 < DIM; k0 += 32) {
    const int k = k0 + lk;
    const int n = ((i & 31) << 3) | (k >> 6);
    const int d = k & 63;
    h8 a = *(const h8*)(out_head + (size_t)((b * NH + hh) * NN + n) * HD + d);
#pragma unroll
    for (int ct = 0; ct < 4; ++ct) {
      h8 bf = ld_f32x8_h8(pw + (size_t)(col0 + ct * 16 + lr) * DIM + k0 + lk);
      acc[ct] = mfma16(a, bf, acc[ct]);
    }
  }
#pragma unroll
  for (int ct = 0; ct < 4; ++ct) {
    int col = col0 + ct * 16 + lr;
    float bias = pb[col];
#pragma unroll
    for (int r = 0; r < 4; ++r) {
      int row = row0 + lg * 4 + r;
      out0[(size_t)row * DIM + col] = acc[ct][r] + bias;
    }
  }
}

// ---------------------------------------------------------------------------
extern "C" void kernel_launch(void* const* d_in, const int* in_sizes, int n_in,
                              void* d_out, int out_size, void* d_ws, size_t ws_size,
                              hipStream_t stream) {
  const float* x = (const float*)d_in[0];
  const float* anchors = (const float*)d_in[1];
  const float* weights = (const float*)d_in[2];
  const float* qk_w = (const float*)d_in[3];
  const float* v_w = (const float*)d_in[4];
  const float* proj_w = (const float*)d_in[5];
  const float* proj_b = (const float*)d_in[6];

  float* out0 = (float*)d_out;                       // [8,256,512]
  float* a0_out = out0 + (size_t)BB * NN * DIM;      // [8,5,8,256,256]

  char* ws = (char*)d_ws;
  half_t* q_h = (half_t*)ws;                                   // 2 MB
  half_t* k_h = (half_t*)(ws + (size_t)2 * 1024 * 1024);       // 1.25 MB
  half_t* vT = (half_t*)(ws + (size_t)4 * 1024 * 1024);        // 2 MB
  half_t* out_head = (half_t*)(ws + (size_t)6 * 1024 * 1024);  // 2 MB
  half_t* U = (half_t*)(ws + (size_t)8 * 1024 * 1024);         // 10 MB

  proj_all<<<dim3(84, 8), 256, 0, stream>>>(x, anchors, qk_w, v_w, q_h, k_h, vT);

  const size_t lds_bytes = 131072 + 4352 + 20480;  // 155,904 B
  fused_attn3<<<dim3(BB * NC * NH), 512, lds_bytes, stream>>>(q_h, k_h, vT, weights,
                                                              a0_out, U);

  reduce_u<<<dim3(512), 256, 0, stream>>>(U, out_head);

  out_proj<<<dim3(32, 8), 256, 0, stream>>>(out_head, proj_w, proj_b, out0);

  (void)in_sizes; (void)n_in; (void)out_size; (void)ws_size;
}

// Round 4
// 159.189 us; speedup vs baseline: 1.4273x; 1.0020x over previous
//
#include <hip/hip_runtime.h>
#include <hip/hip_fp16.h>
#include <cstdint>

// Problem constants
#define BB 8
#define NN 256
#define NC 5
#define NH 8
#define DIM 512
#define HD 64

typedef _Float16 half_t;
typedef _Float16 h8 __attribute__((ext_vector_type(8)));
typedef _Float16 h4 __attribute__((ext_vector_type(4)));
typedef float f4 __attribute__((ext_vector_type(4)));
typedef uint32_t u4v __attribute__((ext_vector_type(4)));

__device__ __forceinline__ f4 mfma16(h8 a, h8 b, f4 c) {
  return __builtin_amdgcn_mfma_f32_16x16x32_f16(a, b, c, 0, 0, 0);
}

__device__ __forceinline__ h8 ld_f32x8_h8(const float* __restrict__ p) {
  float4 a = *(const float4*)p;
  float4 b = *(const float4*)(p + 4);
  h8 r;
  r[0] = (_Float16)a.x; r[1] = (_Float16)a.y; r[2] = (_Float16)a.z; r[3] = (_Float16)a.w;
  r[4] = (_Float16)b.x; r[5] = (_Float16)b.y; r[6] = (_Float16)b.z; r[7] = (_Float16)b.w;
  return r;
}

static __device__ const h8 HZERO = {(_Float16)0, (_Float16)0, (_Float16)0, (_Float16)0,
                                    (_Float16)0, (_Float16)0, (_Float16)0, (_Float16)0};

// relu(x): v_pk_max_f16
__device__ __forceinline__ h8 relu_pos_h8(h8 x) {
#if __has_builtin(__builtin_elementwise_max)
  return __builtin_elementwise_max(x, HZERO);
#else
  u4v u = __builtin_bit_cast(u4v, x);
  const u4v k1 = {0x00010001u, 0x00010001u, 0x00010001u, 0x00010001u};
  u4v s = (u >> 15) & k1;
  u4v m = (s << 16) - s;
  u = u & ~m;
  return __builtin_bit_cast(h8, u);
#endif
}

// relu(-x): v_pk_max_f16 with neg modifier
__device__ __forceinline__ h8 relu_neg_h8(h8 x) {
#if __has_builtin(__builtin_elementwise_max)
  return __builtin_elementwise_max(-x, HZERO);
#else
  u4v u = __builtin_bit_cast(u4v, x);
  const u4v k1 = {0x00010001u, 0x00010001u, 0x00010001u, 0x00010001u};
  const u4v ks = {0x80008000u, 0x80008000u, 0x80008000u, 0x80008000u};
  u4v s = (u >> 15) & k1;
  u4v m = (s << 16) - s;
  u = (u ^ ks) & m;
  return __builtin_bit_cast(h8, u);
#endif
}

// Raw barrier: waits LDS only, does NOT drain vmcnt (global stores stay in flight).
__device__ __forceinline__ void barrier_lds() {
  __builtin_amdgcn_sched_barrier(0);
  asm volatile("s_waitcnt lgkmcnt(0)" ::: "memory");
  __builtin_amdgcn_s_barrier();
  asm volatile("" ::: "memory");
  __builtin_amdgcn_sched_barrier(0);
}

// ---------------------------------------------------------------------------
// K1: all three projections in one launch.
//   bx <  32: q  = x @ qk_w^T       -> q_h [2048][512] fp16
//   bx <  52: k  = anchors @ qk_w^T -> k_h [1280][512] fp16
//   else    : vT = (x @ v_w^T)^T    -> vT  [512][2048] fp16  ([h*64+d][b*256+m])
// ---------------------------------------------------------------------------
__global__ __launch_bounds__(256) void proj_all(const float* __restrict__ x,
                                                const float* __restrict__ anchors,
                                                const float* __restrict__ qk_w,
                                                const float* __restrict__ v_w,
                                                half_t* __restrict__ q_h,
                                                half_t* __restrict__ k_h,
                                                half_t* __restrict__ vT) {
  const int bx = blockIdx.x, by = blockIdx.y;
  const int tid = threadIdx.x;
  const int w = tid >> 6, lane = tid & 63;
  const int lr = lane & 15, lk = (lane >> 4) * 8, lg = lane >> 4;

  const float* A;
  const float* W;
  int mode, rt0;
  if (bx < 32)      { A = x;       W = qk_w; mode = 0; rt0 = bx * 64; }
  else if (bx < 52) { A = anchors; W = qk_w; mode = 1; rt0 = (bx - 32) * 64; }
  else              { A = x;       W = v_w;  mode = 2; rt0 = (bx - 52) * 64; }

  const int row0 = rt0 + w * 16;
  const int col0 = by * 64;
  const f4 fz = {0.f, 0.f, 0.f, 0.f};
  f4 acc[4] = {fz, fz, fz, fz};
  const float* arow = A + (size_t)(row0 + lr) * DIM;

  if (mode != 2) {
    for (int k0 = 0; k0 < DIM; k0 += 32) {
      h8 a = ld_f32x8_h8(arow + k0 + lk);
#pragma unroll
      for (int ct = 0; ct < 4; ++ct) {
        h8 b = ld_f32x8_h8(W + (size_t)(col0 + ct * 16 + lr) * DIM + k0 + lk);
        acc[ct] = mfma16(a, b, acc[ct]);
      }
    }
    half_t* out = (mode == 0) ? q_h : k_h;
#pragma unroll
    for (int ct = 0; ct < 4; ++ct) {
      int col = col0 + ct * 16 + lr;
#pragma unroll
      for (int r = 0; r < 4; ++r) {
        int row = row0 + lg * 4 + r;
        out[(size_t)row * DIM + col] = (half_t)acc[ct][r];
      }
    }
  } else {
    for (int k0 = 0; k0 < DIM; k0 += 32) {
      h8 a = ld_f32x8_h8(arow + k0 + lk);
#pragma unroll
      for (int ct = 0; ct < 4; ++ct) {
        h8 b = ld_f32x8_h8(W + (size_t)(col0 + ct * 16 + lr) * DIM + k0 + lk);
        acc[ct] = mfma16(b, a, acc[ct]);
      }
    }
    const int xrow = row0 + lr;
#pragma unroll
    for (int ct = 0; ct < 4; ++ct) {
#pragma unroll
      for (int r = 0; r < 4; ++r) {
        int col = col0 + ct * 16 + lg * 4 + r;  // = h*64 + d
        vT[(size_t)col * (BB * NN) + xrow] = (half_t)acc[ct][r];
      }
    }
  }
}

// ---------------------------------------------------------------------------
// K2 v4: per (b,c,h) block, 512 threads (8 waves), wave w owns rows n0=w*32.
//  phase1: a0 fragments -> fp32 DIRECT global store + fp16 LDS (h4, swizzled)
//  pair loop pp=0..3 (2 panels = 64 cols each):
//    - prefetch vT B-fragments (both panels)
//    - S panels via MFMA (4 b128 reads + 8 MFMA per kc)
//    - per-wave (max,sum) -> LDS ping-pong, ONE barrier, combine
//    - P transpose-bounce: 4x ds_write_b64 + 16x ds_read_u16 per panel
//    - PV MFMA into uacc
//  store U_c (fp16).
// LDS: a0s 128KB + scr 8KB + pbuf 18KB = 157,696 B. 1 blk/CU, 2 waves/SIMD.
// ---------------------------------------------------------------------------
__global__ __launch_bounds__(512, 1) void fused_attn4(const half_t* __restrict__ q_h,
                                                      const half_t* __restrict__ k_h,
                                                      const half_t* __restrict__ vT,
                                                      const float* __restrict__ weights,
                                                      float* __restrict__ a0_base,
                                                      half_t* __restrict__ U) {
  extern __shared__ char smem[];
  half_t* a0s = (half_t*)smem;                       // [256][256] swizzled, 131072 B
  float2* scr = (float2*)(smem + 131072);            // 2 regions x 2 pan x 8 w x 32
  half_t* pbuf = (half_t*)(smem + 131072 + 8192);    // 8 waves x 32 x 36 h

  const int id = blockIdx.x;
  const int b = id / (NC * NH);
  const int rem = id % (NC * NH);
  const int c = rem / NH;
  const int h = rem % NH;

  const int tid = threadIdx.x;
  const int w = tid >> 6, lane = tid & 63;
  const int lr = lane & 15, lk = (lane >> 4) * 8, lg = lane >> 4;
  const int n0 = w * 32;

  const half_t* qb = q_h + (size_t)(b * NN) * DIM + h * HD;
  const half_t* kb = k_h + (size_t)(c * NN) * DIM + h * HD;
  const half_t* vTb = vT + (size_t)(h * HD) * (BB * NN) + b * NN;
  float* a0out = a0_base + (size_t)((b * NC + c) * NH + h) * (NN * NN);
  const float wgt = weights[(b * NH + h) * NC + c];

  const f4 fz = {0.f, 0.f, 0.f, 0.f};

  // ---- phase 1: a0 fragments -> fp32 global (direct) + fp16 LDS ----
  h8 qf[2][2];
#pragma unroll
  for (int bt = 0; bt < 2; ++bt)
#pragma unroll
    for (int kk = 0; kk < 2; ++kk)
      qf[bt][kk] = *(const h8*)(qb + (size_t)(n0 + bt * 16 + lr) * DIM + kk * 32 + lk);

  const int na = n0 + lr, nb2 = n0 + 16 + lr;
#pragma unroll
  for (int mt = 0; mt < 16; ++mt) {
    h8 kf0 = *(const h8*)(kb + (size_t)(mt * 16 + lr) * DIM + lk);
    h8 kf1 = *(const h8*)(kb + (size_t)(mt * 16 + lr) * DIM + 32 + lk);
    f4 acc0 = fz, acc1 = fz;
    acc0 = mfma16(kf0, qf[0][0], acc0);
    acc0 = mfma16(kf1, qf[0][1], acc0);
    acc1 = mfma16(kf0, qf[1][0], acc1);
    acc1 = mfma16(kf1, qf[1][1], acc1);
    const int mb = mt * 16 + lg * 4;
    // scale
    f4 v0, v1;
#pragma unroll
    for (int r = 0; r < 4; ++r) { v0[r] = acc0[r] * 0.125f; v1[r] = acc1[r] * 0.125f; }
    // direct fp32 store (fire-and-forget; drains under panel compute)
    *(f4*)(a0out + (size_t)na * NN + mb) = v0;
    *(f4*)(a0out + (size_t)nb2 * NN + mb) = v1;
    // fp16 copy to LDS for S
    h4 w0, w1;
#pragma unroll
    for (int r = 0; r < 4; ++r) { w0[r] = (_Float16)v0[r]; w1[r] = (_Float16)v1[r]; }
    *(h4*)(a0s + ((na * NN + mb) ^ ((na & 7) << 3))) = w0;
    *(h4*)(a0s + ((nb2 * NN + mb) ^ ((nb2 & 7) << 3))) = w1;
  }
  barrier_lds();

  // ---- hoist L = relu(-a0) for this wave's 32 rows (64 VGPRs) ----
  h8 La[2][8];
#pragma unroll
  for (int rt = 0; rt < 2; ++rt)
#pragma unroll
    for (int kc = 0; kc < 8; ++kc) {
      int row = n0 + rt * 16 + lr;
      La[rt][kc] = relu_neg_h8(*(const h8*)(a0s + ((row * NN + kc * 32 + lk) ^ ((row & 7) << 3))));
    }

  half_t* pbw = pbuf + w * 1152;  // [32 n'][36] transposed P buffer
  f4 uacc[4][2];
#pragma unroll
  for (int dt = 0; dt < 4; ++dt)
#pragma unroll
    for (int nt = 0; nt < 2; ++nt) uacc[dt][nt] = fz;

#pragma unroll 1
  for (int pp = 0; pp < 4; ++pp) {
    const int p0 = pp * 2;

    // prefetch v^T B-fragments for both panels
    h8 vf[2][4];
#pragma unroll
    for (int pan = 0; pan < 2; ++pan)
#pragma unroll
      for (int dt = 0; dt < 4; ++dt)
        vf[pan][dt] = *(const h8*)(vTb + (size_t)(dt * 16 + lr) * (BB * NN) + (p0 + pan) * 32 + lk);

    // S for both panels: sacc[pan][ctp][rt]
    f4 sacc[2][2][2] = {{{fz, fz}, {fz, fz}}, {{fz, fz}, {fz, fz}}};
#pragma unroll
    for (int kc = 0; kc < 8; ++kc) {
      const int ra = p0 * 32 + lr;
      h8 R00 = relu_pos_h8(*(const h8*)(a0s + (((ra) * NN + kc * 32 + lk) ^ ((ra & 7) << 3))));
      const int rb = p0 * 32 + 16 + lr;
      h8 R01 = relu_pos_h8(*(const h8*)(a0s + (((rb) * NN + kc * 32 + lk) ^ ((rb & 7) << 3))));
      const int rc = p0 * 32 + 32 + lr;
      h8 R10 = relu_pos_h8(*(const h8*)(a0s + (((rc) * NN + kc * 32 + lk) ^ ((rc & 7) << 3))));
      const int rd = p0 * 32 + 48 + lr;
      h8 R11 = relu_pos_h8(*(const h8*)(a0s + (((rd) * NN + kc * 32 + lk) ^ ((rd & 7) << 3))));
      sacc[0][0][0] = mfma16(La[0][kc], R00, sacc[0][0][0]);
      sacc[0][0][1] = mfma16(La[1][kc], R00, sacc[0][0][1]);
      sacc[0][1][0] = mfma16(La[0][kc], R01, sacc[0][1][0]);
      sacc[0][1][1] = mfma16(La[1][kc], R01, sacc[0][1][1]);
      sacc[1][0][0] = mfma16(La[0][kc], R10, sacc[1][0][0]);
      sacc[1][0][1] = mfma16(La[1][kc], R10, sacc[1][0][1]);
      sacc[1][1][0] = mfma16(La[0][kc], R11, sacc[1][1][0]);
      sacc[1][1][1] = mfma16(La[1][kc], R11, sacc[1][1][1]);
    }

    // per-wave (max, sum) for each panel/ctp; exp applied in place
    float mw[2][2], sw[2][2];
#pragma unroll
    for (int pan = 0; pan < 2; ++pan)
#pragma unroll
      for (int ctp = 0; ctp < 2; ++ctp) {
        float v = -3e38f;
#pragma unroll
        for (int rt = 0; rt < 2; ++rt)
#pragma unroll
          for (int r = 0; r < 4; ++r) v = fmaxf(v, sacc[pan][ctp][rt][r]);
        v = fmaxf(v, __shfl_xor(v, 16, 64));
        v = fmaxf(v, __shfl_xor(v, 32, 64));
        mw[pan][ctp] = v;
        float s = 0.f;
#pragma unroll
        for (int rt = 0; rt < 2; ++rt)
#pragma unroll
          for (int r = 0; r < 4; ++r) {
            float e = __expf(sacc[pan][ctp][rt][r] - v);
            sacc[pan][ctp][rt][r] = e;
            s += e;
          }
        s += __shfl_xor(s, 16, 64);
        s += __shfl_xor(s, 32, 64);
        sw[pan][ctp] = s;
      }

    float2* sp = scr + (pp & 1) * 512;
    if (lane < 16) {
#pragma unroll
      for (int pan = 0; pan < 2; ++pan) {
        float2 t0; t0.x = mw[pan][0]; t0.y = sw[pan][0];
        float2 t1; t1.x = mw[pan][1]; t1.y = sw[pan][1];
        sp[pan * 256 + w * 32 + lr] = t0;
        sp[pan * 256 + w * 32 + 16 + lr] = t1;
      }
    }
    barrier_lds();

    float fac[2][2];
#pragma unroll
    for (int pan = 0; pan < 2; ++pan)
#pragma unroll
      for (int ctp = 0; ctp < 2; ++ctp) {
        float2 t[8];
        float gm = -3e38f;
#pragma unroll
        for (int ww = 0; ww < 8; ++ww) {
          t[ww] = sp[pan * 256 + ww * 32 + ctp * 16 + lr];
          gm = fmaxf(gm, t[ww].x);
        }
        float sg = 0.f;
#pragma unroll
        for (int ww = 0; ww < 8; ++ww) sg += t[ww].y * __expf(t[ww].x - gm);
        fac[pan][ctp] = __expf(mw[pan][ctp] - gm) * wgt / sg;
      }

    // P transpose-bounce + PV, per panel (sequential pbw reuse)
#pragma unroll
    for (int pan = 0; pan < 2; ++pan) {
#pragma unroll
      for (int ctp = 0; ctp < 2; ++ctp) {
        const float f = fac[pan][ctp];
#pragma unroll
        for (int rt = 0; rt < 2; ++rt) {
          h4 hv;
#pragma unroll
          for (int r = 0; r < 4; ++r) hv[r] = (_Float16)(sacc[pan][ctp][rt][r] * f);
          // transposed: [n'=ctp*16+lr][n=rt*16+lg*4 .. +3]
          *(h4*)(pbw + (ctp * 16 + lr) * 36 + rt * 16 + lg * 4) = hv;
        }
      }
      h8 pf0, pf1;
#pragma unroll
      for (int e = 0; e < 8; ++e) {
        pf0[e] = pbw[(lk + e) * 36 + lr];
        pf1[e] = pbw[(lk + e) * 36 + 16 + lr];
      }
#pragma unroll
      for (int dt = 0; dt < 4; ++dt) {
        uacc[dt][0] = mfma16(vf[pan][dt], pf0, uacc[dt][0]);
        uacc[dt][1] = mfma16(vf[pan][dt], pf1, uacc[dt][1]);
      }
    }
  }

  // ---- store U_c (fp16): D[i=d][j=n] ----
  half_t* Ub = U + (size_t)((b * NC + c) * NH + h) * (NN * HD);
#pragma unroll
  for (int dt = 0; dt < 4; ++dt)
#pragma unroll
    for (int nt = 0; nt < 2; ++nt) {
      int d = dt * 16 + lg * 4;
      int n = n0 + nt * 16 + lr;
      h4 hv;
#pragma unroll
      for (int r = 0; r < 4; ++r) hv[r] = (_Float16)uacc[dt][nt][r];
      *(h4*)(Ub + (size_t)n * HD + d) = hv;
    }
}

// ---------------------------------------------------------------------------
// K3: out_head[b,h] = sum_c U[(b,c,h)]  (weights already folded into U)
// ---------------------------------------------------------------------------
__global__ __launch_bounds__(256) void reduce_u(const half_t* __restrict__ U,
                                                half_t* __restrict__ out_head) {
  int t = blockIdx.x * 256 + threadIdx.x;  // 131072 threads
  int bh = t >> 11;
  int e = (t & 2047) * 8;
  int b = bh >> 3, h = bh & 7;
  float acc[8] = {0.f, 0.f, 0.f, 0.f, 0.f, 0.f, 0.f, 0.f};
#pragma unroll
  for (int c = 0; c < NC; ++c) {
    h8 u = *(const h8*)(U + (size_t)((b * NC + c) * NH + h) * (NN * HD) + e);
#pragma unroll
    for (int j = 0; j < 8; ++j) acc[j] += (float)u[j];
  }
  h8 o;
#pragma unroll
  for (int j = 0; j < 8; ++j) o[j] = (_Float16)acc[j];
  *(h8*)(out_head + (size_t)bh * (NN * HD) + e) = o;
}

// ---------------------------------------------------------------------------
// K4: out0 = reshape(out_head) @ proj_w^T + proj_b
// ---------------------------------------------------------------------------
__global__ __launch_bounds__(256) void out_proj(const half_t* __restrict__ out_head,
                                                const float* __restrict__ pw,
                                                const float* __restrict__ pb,
                                                float* __restrict__ out0) {
  const int tid = threadIdx.x;
  const int w = tid >> 6, lane = tid & 63;
  const int lr = lane & 15, lk = (lane >> 4) * 8, lg = lane >> 4;
  const int row0 = blockIdx.x * 64 + w * 16;
  const int col0 = blockIdx.y * 64;
  const int r_ = row0 + lr;
  const int b = r_ >> 8, i = r_ & 255;
  const int hh = i >> 5;
  const f4 fz = {0.f, 0.f, 0.f, 0.f};
  f4 acc[4] = {fz, fz, fz, fz};
  for (int k0 = 0; k0 < DIM; k0 += 32) {
    const int k = k0 + lk;
    const int n = ((i & 31) << 3) | (k >> 6);
    const int d = k & 63;
    h8 a = *(const h8*)(out_head + (size_t)((b * NH + hh) * NN + n) * HD + d);
#pragma unroll
    for (int ct = 0; ct < 4; ++ct) {
      h8 bf = ld_f32x8_h8(pw + (size_t)(col0 + ct * 16 + lr) * DIM + k0 + lk);
      acc[ct] = mfma16(a, bf, acc[ct]);
    }
  }
#pragma unroll
  for (int ct = 0; ct < 4; ++ct) {
    int col = col0 + ct * 16 + lr;
    float bias = pb[col];
#pragma unroll
    for (int r = 0; r < 4; ++r) {
      int row = row0 + lg * 4 + r;
      out0[(size_t)row * DIM + col] = acc[ct][r] + bias;
    }
  }
}

// ---------------------------------------------------------------------------
extern "C" void kernel_launch(void* const* d_in, const int* in_sizes, int n_in,
                              void* d_out, int out_size, void* d_ws, size_t ws_size,
                              hipStream_t stream) {
  const float* x = (const float*)d_in[0];
  const float* anchors = (const float*)d_in[1];
  const float* weights = (const float*)d_in[2];
  const float* qk_w = (const float*)d_in[3];
  const float* v_w = (const float*)d_in[4];
  const float* proj_w = (const float*)d_in[5];
  const float* proj_b = (const float*)d_in[6];

  float* out0 = (float*)d_out;                       // [8,256,512]
  float* a0_out = out0 + (size_t)BB * NN * DIM;      // [8,5,8,256,256]

  char* ws = (char*)d_ws;
  half_t* q_h = (half_t*)ws;                                   // 2 MB
  half_t* k_h = (half_t*)(ws + (size_t)2 * 1024 * 1024);       // 1.25 MB
  half_t* vT = (half_t*)(ws + (size_t)4 * 1024 * 1024);        // 2 MB
  half_t* out_head = (half_t*)(ws + (size_t)6 * 1024 * 1024);  // 2 MB
  half_t* U = (half_t*)(ws + (size_t)8 * 1024 * 1024);         // 10.5 MB

  proj_all<<<dim3(84, 8), 256, 0, stream>>>(x, anchors, qk_w, v_w, q_h, k_h, vT);

  const size_t lds_bytes = 131072 + 8192 + 18432;  // 157,696 B
  fused_attn4<<<dim3(BB * NC * NH), 512, lds_bytes, stream>>>(q_h, k_h, vT, weights,
                                                              a0_out, U);

  reduce_u<<<dim3(512), 256, 0, stream>>>(U, out_head);

  out_proj<<<dim3(32, 8), 256, 0, stream>>>(out_head, proj_w, proj_b, out0);

  (void)in_sizes; (void)n_in; (void)out_size; (void)ws_size;
}

// Round 5
// 151.119 us; speedup vs baseline: 1.5035x; 1.0534x over previous
//
#include <hip/hip_runtime.h>
#include <hip/hip_fp16.h>
#include <cstdint>

// Problem constants
#define BB 8
#define NN 256
#define NC 5
#define NH 8
#define DIM 512
#define HD 64

typedef _Float16 half_t;
typedef _Float16 h8 __attribute__((ext_vector_type(8)));
typedef _Float16 h4 __attribute__((ext_vector_type(4)));
typedef float f4 __attribute__((ext_vector_type(4)));
typedef uint32_t u4v __attribute__((ext_vector_type(4)));

__device__ __forceinline__ f4 mfma16(h8 a, h8 b, f4 c) {
  return __builtin_amdgcn_mfma_f32_16x16x32_f16(a, b, c, 0, 0, 0);
}

__device__ __forceinline__ h8 ld_f32x8_h8(const float* __restrict__ p) {
  float4 a = *(const float4*)p;
  float4 b = *(const float4*)(p + 4);
  h8 r;
  r[0] = (_Float16)a.x; r[1] = (_Float16)a.y; r[2] = (_Float16)a.z; r[3] = (_Float16)a.w;
  r[4] = (_Float16)b.x; r[5] = (_Float16)b.y; r[6] = (_Float16)b.z; r[7] = (_Float16)b.w;
  return r;
}

static __device__ const h8 HZERO = {(_Float16)0, (_Float16)0, (_Float16)0, (_Float16)0,
                                    (_Float16)0, (_Float16)0, (_Float16)0, (_Float16)0};

__device__ __forceinline__ h8 relu_pos_h8(h8 x) {
#if __has_builtin(__builtin_elementwise_max)
  return __builtin_elementwise_max(x, HZERO);
#else
  u4v u = __builtin_bit_cast(u4v, x);
  const u4v k1 = {0x00010001u, 0x00010001u, 0x00010001u, 0x00010001u};
  u4v s = (u >> 15) & k1;
  u4v m = (s << 16) - s;
  u = u & ~m;
  return __builtin_bit_cast(h8, u);
#endif
}

__device__ __forceinline__ h8 relu_neg_h8(h8 x) {
#if __has_builtin(__builtin_elementwise_max)
  return __builtin_elementwise_max(-x, HZERO);
#else
  u4v u = __builtin_bit_cast(u4v, x);
  const u4v k1 = {0x00010001u, 0x00010001u, 0x00010001u, 0x00010001u};
  const u4v ks = {0x80008000u, 0x80008000u, 0x80008000u, 0x80008000u};
  u4v s = (u >> 15) & k1;
  u4v m = (s << 16) - s;
  u = (u ^ ks) & m;
  return __builtin_bit_cast(h8, u);
#endif
}

// Raw barrier: waits LDS only, does NOT drain vmcnt (global stores stay in flight).
__device__ __forceinline__ void barrier_lds() {
  __builtin_amdgcn_sched_barrier(0);
  asm volatile("s_waitcnt lgkmcnt(0)" ::: "memory");
  __builtin_amdgcn_s_barrier();
  asm volatile("" ::: "memory");
  __builtin_amdgcn_sched_barrier(0);
}

// ---------------------------------------------------------------------------
// K1: all three projections in one launch.
//   bx <  32: q  = x @ qk_w^T       -> q_h [2048][512] fp16
//   bx <  52: k  = anchors @ qk_w^T -> k_h [1280][512] fp16
//   else    : vT = (x @ v_w^T)^T    -> vT  [512][2048] fp16  ([h*64+d][b*256+m])
// ---------------------------------------------------------------------------
__global__ __launch_bounds__(256) void proj_all(const float* __restrict__ x,
                                                const float* __restrict__ anchors,
                                                const float* __restrict__ qk_w,
                                                const float* __restrict__ v_w,
                                                half_t* __restrict__ q_h,
                                                half_t* __restrict__ k_h,
                                                half_t* __restrict__ vT) {
  const int bx = blockIdx.x, by = blockIdx.y;
  const int tid = threadIdx.x;
  const int w = tid >> 6, lane = tid & 63;
  const int lr = lane & 15, lk = (lane >> 4) * 8, lg = lane >> 4;

  const float* A;
  const float* W;
  int mode, rt0;
  if (bx < 32)      { A = x;       W = qk_w; mode = 0; rt0 = bx * 64; }
  else if (bx < 52) { A = anchors; W = qk_w; mode = 1; rt0 = (bx - 32) * 64; }
  else              { A = x;       W = v_w;  mode = 2; rt0 = (bx - 52) * 64; }

  const int row0 = rt0 + w * 16;
  const int col0 = by * 64;
  const f4 fz = {0.f, 0.f, 0.f, 0.f};
  f4 acc[4] = {fz, fz, fz, fz};
  const float* arow = A + (size_t)(row0 + lr) * DIM;

  if (mode != 2) {
    for (int k0 = 0; k0 < DIM; k0 += 32) {
      h8 a = ld_f32x8_h8(arow + k0 + lk);
#pragma unroll
      for (int ct = 0; ct < 4; ++ct) {
        h8 b = ld_f32x8_h8(W + (size_t)(col0 + ct * 16 + lr) * DIM + k0 + lk);
        acc[ct] = mfma16(a, b, acc[ct]);
      }
    }
    half_t* out = (mode == 0) ? q_h : k_h;
#pragma unroll
    for (int ct = 0; ct < 4; ++ct) {
      int col = col0 + ct * 16 + lr;
#pragma unroll
      for (int r = 0; r < 4; ++r) {
        int row = row0 + lg * 4 + r;
        out[(size_t)row * DIM + col] = (half_t)acc[ct][r];
      }
    }
  } else {
    for (int k0 = 0; k0 < DIM; k0 += 32) {
      h8 a = ld_f32x8_h8(arow + k0 + lk);
#pragma unroll
      for (int ct = 0; ct < 4; ++ct) {
        h8 b = ld_f32x8_h8(W + (size_t)(col0 + ct * 16 + lr) * DIM + k0 + lk);
        acc[ct] = mfma16(b, a, acc[ct]);
      }
    }
    const int xrow = row0 + lr;
#pragma unroll
    for (int ct = 0; ct < 4; ++ct) {
#pragma unroll
      for (int r = 0; r < 4; ++r) {
        int col = col0 + ct * 16 + lg * 4 + r;  // = h*64 + d
        vT[(size_t)col * (BB * NN) + xrow] = (half_t)acc[ct][r];
      }
    }
  }
}

// ---------------------------------------------------------------------------
// K2 v5: 2 half-blocks per (b,c,h) (split on R rows m'). 1024 thr, 16 waves,
// wave w owns L rows n0=w*16 (kept in registers via per-wave LDS bounce).
//  stage k-tile -> barrier A
//  phase1: full a0 per block; La from bounce; half's rows -> global fp32 + LDS fp16
//  barrier B; stage vT half-tile (into dead kst region)
//  S = relu(-a0) @ relu(a0_half)^T : sacc[8] (128 m' columns)
//  softmax: per-wave (max,sum) -> scr; barrier C; waves 0-1 combine -> scr2;
//  barrier D; fac; PV per 32-col panel via per-wave transpose bounce.
//  store partial U4 (fp16).
// LDS: a0s 64K + kst 32K (vst 16K reuse) + wbuf 20K + scr 16K + scr2 1K = 133 KiB
// ---------------------------------------------------------------------------
__global__ __launch_bounds__(1024, 4) void fused_attn5(const half_t* __restrict__ q_h,
                                                       const half_t* __restrict__ k_h,
                                                       const half_t* __restrict__ vT,
                                                       const float* __restrict__ weights,
                                                       float* __restrict__ a0_base,
                                                       half_t* __restrict__ U4) {
  extern __shared__ char smem[];
  half_t* a0s = (half_t*)smem;                        // [128][256] swz, 65536 B
  half_t* kst = (half_t*)(smem + 65536);              // [256][64] swz, 32768 B
  half_t* vst = kst;                                  // reuse: [64][128] swz, 16384 B
  half_t* wbuf = (half_t*)(smem + 98304);             // 16 waves x 640 h (1280 B)
  float2* scr = (float2*)(smem + 118784);             // [16 w][128 m'] f2, 16384 B
  float2* scr2 = (float2*)(smem + 135168);            // [128 m'] f2 (gm, sg), 1024 B

  const int id = blockIdx.x;          // 640 = 8*5*8*2
  const int b = id / 80;
  const int rem = id % 80;
  const int c = rem / 16;
  const int h = (rem >> 1) & 7;
  const int q = rem & 1;

  const int tid = threadIdx.x;
  const int w = tid >> 6, lane = tid & 63;
  const int lr = lane & 15, lk = (lane >> 4) * 8, lg = lane >> 4;
  const int n0 = w * 16;

  const half_t* qb = q_h + (size_t)(b * NN) * DIM + h * HD;
  const half_t* kb = k_h + (size_t)(c * NN) * DIM + h * HD;
  const half_t* vTb = vT + (size_t)(h * HD) * (BB * NN) + b * NN;
  float* a0out = a0_base + (size_t)((b * NC + c) * NH + h) * (NN * NN);
  const float wgt = weights[(b * NH + h) * NC + c];

  const f4 fz = {0.f, 0.f, 0.f, 0.f};

  // q fragments for this wave's 16 rows (global; not redundant within block)
  h8 qf0 = *(const h8*)(qb + (size_t)(n0 + lr) * DIM + lk);
  h8 qf1 = *(const h8*)(qb + (size_t)(n0 + lr) * DIM + 32 + lk);

  // ---- stage k tile [256][64] fp16, swizzled ----
#pragma unroll
  for (int pass = 0; pass < 2; ++pass) {
    int slot = pass * 1024 + tid;
    int row = slot >> 3, k8 = (slot & 7) * 8;
    h8 val = *(const h8*)(kb + (size_t)row * DIM + k8);
    *(h8*)(kst + ((row * 64 + k8) ^ ((row & 7) << 3))) = val;
  }
  barrier_lds();  // A

  // ---- phase 1: full a0 for L; half rows -> global fp32 + LDS fp16 ----
  half_t* Lb = wbuf + w * 640;  // [16][40]
  h8 La[8];
  const bool myhalf = ((w >> 3) == q);
  const int rl = (w & 7) * 16 + lr;  // local a0s row when myhalf
#pragma unroll
  for (int mt = 0; mt < 16; ++mt) {
    const int krow = mt * 16 + lr;
    h8 kf0 = *(const h8*)(kst + ((krow * 64 + lk) ^ ((krow & 7) << 3)));
    h8 kf1 = *(const h8*)(kst + ((krow * 64 + 32 + lk) ^ ((krow & 7) << 3)));
    f4 acc = mfma16(kf0, qf0, fz);
    acc = mfma16(kf1, qf1, acc);
    f4 v0;
    h4 hv;
#pragma unroll
    for (int r = 0; r < 4; ++r) {
      v0[r] = acc[r] * 0.125f;
      hv[r] = (_Float16)v0[r];
    }
    *(h4*)(Lb + lr * 40 + (mt & 1) * 16 + lg * 4) = hv;
    if (myhalf) {
      *(f4*)(a0out + (size_t)(n0 + lr) * NN + mt * 16 + lg * 4) = v0;
      *(h4*)(a0s + ((rl * 256 + mt * 16 + lg * 4) ^ ((rl & 7) << 3))) = hv;
    }
    if (mt & 1) {
      h8 raw = *(const h8*)(Lb + lr * 40 + lg * 8);
      La[mt >> 1] = relu_neg_h8(raw);
    }
  }
  barrier_lds();  // B (a0s ready; kst reads done)

  // ---- stage vT half-tile [64 d][128 m'] into dead kst region ----
  {
    int d = tid >> 4, m8 = (tid & 15) * 8;
    h8 val = *(const h8*)(vTb + (size_t)d * (BB * NN) + q * 128 + m8);
    *(h8*)(vst + ((d * 128 + m8) ^ ((d & 7) << 4))) = val;
  }

  // ---- S = L @ R^T over this block's 128 m' columns ----
  f4 sacc[8];
#pragma unroll
  for (int ct = 0; ct < 8; ++ct) sacc[ct] = fz;
#pragma unroll
  for (int kc = 0; kc < 8; ++kc) {
#pragma unroll
    for (int ct = 0; ct < 8; ++ct) {
      const int rr = ct * 16 + lr;
      h8 R = relu_pos_h8(*(const h8*)(a0s + ((rr * 256 + kc * 32 + lk) ^ ((rr & 7) << 3))));
      sacc[ct] = mfma16(La[kc], R, sacc[ct]);
    }
  }

  // ---- per-wave (max, sum) per column; exp in place ----
  float mw[8];
#pragma unroll
  for (int ct = 0; ct < 8; ++ct) {
    float v = 0.f;  // S >= 0 always
#pragma unroll
    for (int r = 0; r < 4; ++r) v = fmaxf(v, sacc[ct][r]);
    v = fmaxf(v, __shfl_xor(v, 16, 64));
    v = fmaxf(v, __shfl_xor(v, 32, 64));
    mw[ct] = v;
    float s = 0.f;
#pragma unroll
    for (int r = 0; r < 4; ++r) {
      float e = __expf(sacc[ct][r] - v);
      sacc[ct][r] = e;
      s += e;
    }
    s += __shfl_xor(s, 16, 64);
    s += __shfl_xor(s, 32, 64);
    if (lane < 16) {
      float2 t;
      t.x = v;
      t.y = s;
      scr[w * 128 + ct * 16 + lr] = t;
    }
  }
  barrier_lds();  // C

  // ---- combine across 16 waves: 128 threads, one column each ----
  if (tid < 128) {
    float gm = 0.f;
#pragma unroll
    for (int ww = 0; ww < 16; ++ww) gm = fmaxf(gm, scr[ww * 128 + tid].x);
    float sg = 0.f;
#pragma unroll
    for (int ww = 0; ww < 16; ++ww) {
      float2 t = scr[ww * 128 + tid];
      sg += t.y * __expf(t.x - gm);
    }
    float2 r;
    r.x = gm;
    r.y = sg;
    scr2[tid] = r;
  }
  barrier_lds();  // D

  float fac[8];
#pragma unroll
  for (int ct = 0; ct < 8; ++ct) {
    float2 t = scr2[ct * 16 + lr];
    fac[ct] = __expf(mw[ct] - t.x) * wgt / t.y;
  }

  // ---- PV: per 32-col panel, transpose-bounce P then MFMA with vst ----
  half_t* pbw = wbuf + w * 640;  // [32][20]
  f4 uacc[4] = {fz, fz, fz, fz};
#pragma unroll
  for (int pan = 0; pan < 4; ++pan) {
#pragma unroll
    for (int ctl = 0; ctl < 2; ++ctl) {
      const int ct = pan * 2 + ctl;
      h4 hv;
#pragma unroll
      for (int r = 0; r < 4; ++r) hv[r] = (_Float16)(sacc[ct][r] * fac[ct]);
      *(h4*)(pbw + (ctl * 16 + lr) * 20 + lg * 4) = hv;
    }
    h8 pf;
#pragma unroll
    for (int e = 0; e < 8; ++e) pf[e] = pbw[(lg * 8 + e) * 20 + lr];
#pragma unroll
    for (int dt = 0; dt < 4; ++dt) {
      const int dr = dt * 16 + lr;
      h8 vf = *(const h8*)(vst + ((dr * 128 + pan * 32 + lk) ^ ((dr & 7) << 4)));
      uacc[dt] = mfma16(vf, pf, uacc[dt]);
    }
  }

  // ---- store partial U4 (fp16): [n][d] ----
  half_t* U4b = U4 + (size_t)(((b * NC + c) * NH + h) * 2 + q) * (NN * HD);
#pragma unroll
  for (int dt = 0; dt < 4; ++dt) {
    h4 hv;
#pragma unroll
    for (int r = 0; r < 4; ++r) hv[r] = (_Float16)uacc[dt][r];
    *(h4*)(U4b + (size_t)(n0 + lr) * HD + dt * 16 + lg * 4) = hv;
  }
}

// ---------------------------------------------------------------------------
// K3: out_head[b,h] = sum over (c, half) of U4 partials
// ---------------------------------------------------------------------------
__global__ __launch_bounds__(256) void reduce_u(const half_t* __restrict__ U4,
                                                half_t* __restrict__ out_head) {
  int t = blockIdx.x * 256 + threadIdx.x;  // 131072 threads
  int bh = t >> 11;
  int e = (t & 2047) * 8;
  int b = bh >> 3, h = bh & 7;
  float acc[8] = {0.f, 0.f, 0.f, 0.f, 0.f, 0.f, 0.f, 0.f};
#pragma unroll
  for (int c = 0; c < NC; ++c)
#pragma unroll
    for (int qq = 0; qq < 2; ++qq) {
      h8 u = *(const h8*)(U4 + (size_t)(((b * NC + c) * NH + h) * 2 + qq) * (NN * HD) + e);
#pragma unroll
      for (int j = 0; j < 8; ++j) acc[j] += (float)u[j];
    }
  h8 o;
#pragma unroll
  for (int j = 0; j < 8; ++j) o[j] = (_Float16)acc[j];
  *(h8*)(out_head + (size_t)bh * (NN * HD) + e) = o;
}

// ---------------------------------------------------------------------------
// K4: out0 = reshape(out_head) @ proj_w^T + proj_b
// ---------------------------------------------------------------------------
__global__ __launch_bounds__(256) void out_proj(const half_t* __restrict__ out_head,
                                                const float* __restrict__ pw,
                                                const float* __restrict__ pb,
                                                float* __restrict__ out0) {
  const int tid = threadIdx.x;
  const int w = tid >> 6, lane = tid & 63;
  const int lr = lane & 15, lk = (lane >> 4) * 8, lg = lane >> 4;
  const int row0 = blockIdx.x * 64 + w * 16;
  const int col0 = blockIdx.y * 64;
  const int r_ = row0 + lr;
  const int b = r_ >> 8, i = r_ & 255;
  const int hh = i >> 5;
  const f4 fz = {0.f, 0.f, 0.f, 0.f};
  f4 acc[4] = {fz, fz, fz, fz};
  for (int k0 = 0; k0 < DIM; k0 += 32) {
    const int k = k0 + lk;
    const int n = ((i & 31) << 3) | (k >> 6);
    const int d = k & 63;
    h8 a = *(const h8*)(out_head + (size_t)((b * NH + hh) * NN + n) * HD + d);
#pragma unroll
    for (int ct = 0; ct < 4; ++ct) {
      h8 bf = ld_f32x8_h8(pw + (size_t)(col0 + ct * 16 + lr) * DIM + k0 + lk);
      acc[ct] = mfma16(a, bf, acc[ct]);
    }
  }
#pragma unroll
  for (int ct = 0; ct < 4; ++ct) {
    int col = col0 + ct * 16 + lr;
    float bias = pb[col];
#pragma unroll
    for (int r = 0; r < 4; ++r) {
      int row = row0 + lg * 4 + r;
      out0[(size_t)row * DIM + col] = acc[ct][r] + bias;
    }
  }
}

// ---------------------------------------------------------------------------
extern "C" void kernel_launch(void* const* d_in, const int* in_sizes, int n_in,
                              void* d_out, int out_size, void* d_ws, size_t ws_size,
                              hipStream_t stream) {
  const float* x = (const float*)d_in[0];
  const float* anchors = (const float*)d_in[1];
  const float* weights = (const float*)d_in[2];
  const float* qk_w = (const float*)d_in[3];
  const float* v_w = (const float*)d_in[4];
  const float* proj_w = (const float*)d_in[5];
  const float* proj_b = (const float*)d_in[6];

  float* out0 = (float*)d_out;                       // [8,256,512]
  float* a0_out = out0 + (size_t)BB * NN * DIM;      // [8,5,8,256,256]

  char* ws = (char*)d_ws;
  half_t* q_h = (half_t*)ws;                                   // 2 MB
  half_t* k_h = (half_t*)(ws + (size_t)2 * 1024 * 1024);       // 1.25 MB
  half_t* vT = (half_t*)(ws + (size_t)4 * 1024 * 1024);        // 2 MB
  half_t* out_head = (half_t*)(ws + (size_t)6 * 1024 * 1024);  // 2 MB
  half_t* U4 = (half_t*)(ws + (size_t)8 * 1024 * 1024);        // 20 MB

  proj_all<<<dim3(84, 8), 256, 0, stream>>>(x, anchors, qk_w, v_w, q_h, k_h, vT);

  const size_t lds_bytes = 65536 + 32768 + 20480 + 16384 + 1024;  // 136,192 B
  fused_attn5<<<dim3(BB * NC * NH * 2), 1024, lds_bytes, stream>>>(q_h, k_h, vT, weights,
                                                                   a0_out, U4);

  reduce_u<<<dim3(512), 256, 0, stream>>>(U4, out_head);

  out_proj<<<dim3(32, 8), 256, 0, stream>>>(out_head, proj_w, proj_b, out0);

  (void)in_sizes; (void)n_in; (void)out_size; (void)ws_size;
}